// Round 1
// baseline (1809.944 us; speedup 1.0000x reference)
//
#include <hip/hip_runtime.h>
#include <math.h>

// S6 (Mamba-style) block, B=2 S=2048 Dm=768 Di=1536 Ds=16 K=4, all f32.
// Round 1: correctness-first f32 pipeline. See journal: next = bf16 MFMA GEMMs.

#define DM   768
#define DI   1536
#define DS2  16
#define SEQN 2048
#define BSZ  2
#define NROWS (BSZ*SEQN)   // 4096

// ---------------- K1: per-row inverse RMS of x ----------------
__global__ __launch_bounds__(256) void rms_k(const float* __restrict__ x,
                                             float* __restrict__ rinv) {
  int wv = threadIdx.x >> 6, lane = threadIdx.x & 63;
  int row = blockIdx.x * 4 + wv;            // 4096 rows, grid=1024
  const float* xr = x + (size_t)row * DM;
  float s = 0.f;
#pragma unroll
  for (int i = 0; i < DM / 64; ++i) { float v = xr[lane + i * 64]; s = fmaf(v, v, s); }
#pragma unroll
  for (int off = 32; off >= 1; off >>= 1) s += __shfl_xor(s, off, 64);
  if (lane == 0) rinv[row] = rsqrtf(s * (1.f / DM) + 1e-6f);
}

// ---------------- generic f32 GEMM: C = [res +] (rowscale*colscale*A) @ B ---
// 128x128 tile, BK=16, 256 threads, 8x8 per thread.
// Micro-tile mapping: m = ty*8+i (A reads broadcast), n = tx + j*16 (B reads
// conflict-free stride-1 across lanes).
__global__ __launch_bounds__(256) void gemm_f32(
    const float* __restrict__ A, int lda,
    const float* __restrict__ B, int ldb,
    float* __restrict__ C, int ldc, int K,
    const float* __restrict__ rowscale,  // optional per-row scale of A (rmsnorm)
    const float* __restrict__ colscale,  // optional per-k scale of A (norm_w)
    const float* __restrict__ res, int ldr)  // optional residual add
{
  __shared__ float As[16][130];   // [k][m], padded: staging scatter <=2-way
  __shared__ float Bs[16][128];   // [k][n]
  const int tid = threadIdx.x;
  const int m0 = blockIdx.y * 128, n0 = blockIdx.x * 128;
  const int tx = tid & 15, ty = tid >> 4;
  float acc[8][8];
#pragma unroll
  for (int i = 0; i < 8; ++i)
#pragma unroll
    for (int j = 0; j < 8; ++j) acc[i][j] = 0.f;

  for (int k0 = 0; k0 < K; k0 += 16) {
    __syncthreads();  // protect LDS from previous iteration's readers
#pragma unroll
    for (int r = 0; r < 2; ++r) {           // A tile: 128 rows x 16 k
      int idx = tid + r * 256;              // 0..511 float4s
      int row = idx >> 2;
      int kq = (idx & 3) << 2;
      float4 v = *reinterpret_cast<const float4*>(&A[(size_t)(m0 + row) * lda + k0 + kq]);
      if (rowscale) { float rs = rowscale[m0 + row]; v.x *= rs; v.y *= rs; v.z *= rs; v.w *= rs; }
      if (colscale) {
        const float4 cs = *reinterpret_cast<const float4*>(&colscale[k0 + kq]);
        v.x *= cs.x; v.y *= cs.y; v.z *= cs.z; v.w *= cs.w;
      }
      As[kq + 0][row] = v.x; As[kq + 1][row] = v.y;
      As[kq + 2][row] = v.z; As[kq + 3][row] = v.w;
    }
#pragma unroll
    for (int r = 0; r < 2; ++r) {           // B tile: 16 k x 128 n
      int idx = tid + r * 256;
      int row = idx >> 5;
      int nq = (idx & 31) << 2;
      *reinterpret_cast<float4*>(&Bs[row][nq]) =
          *reinterpret_cast<const float4*>(&B[(size_t)(k0 + row) * ldb + n0 + nq]);
    }
    __syncthreads();
#pragma unroll
    for (int k = 0; k < 16; ++k) {
      float av[8], bv[8];
#pragma unroll
      for (int i = 0; i < 8; ++i) av[i] = As[k][ty * 8 + i];
#pragma unroll
      for (int j = 0; j < 8; ++j) bv[j] = Bs[k][tx + j * 16];
#pragma unroll
      for (int i = 0; i < 8; ++i)
#pragma unroll
        for (int j = 0; j < 8; ++j) acc[i][j] = fmaf(av[i], bv[j], acc[i][j]);
    }
  }
#pragma unroll
  for (int i = 0; i < 8; ++i) {
    int m = m0 + ty * 8 + i;
#pragma unroll
    for (int j = 0; j < 8; ++j) {
      int n = n0 + tx + j * 16;
      float v = acc[i][j];
      if (res) v += res[(size_t)m * ldr + n];
      C[(size_t)m * ldc + n] = v;
    }
  }
}

// ---------------- K3: depthwise causal conv(K=4) + bias + SiLU -------------
// reads x_main_raw = xz[:, 0:1536] (row stride 3072), writes xc (4096,1536)
__global__ __launch_bounds__(256) void conv_silu_k(const float* __restrict__ xz,
                                                   const float* __restrict__ cw,
                                                   const float* __restrict__ cb,
                                                   float* __restrict__ xc) {
  int idx = blockIdx.x * 256 + threadIdx.x;  // over 4096*1536
  int d = idx % DI;
  int bt = idx / DI;       // 0..4095
  int t = bt & (SEQN - 1);
  float acc = cb[d];
  const float4 w4 = *reinterpret_cast<const float4*>(&cw[d * 4]);
  const float wv[4] = {w4.x, w4.y, w4.z, w4.w};
  const float* base = xz + (size_t)bt * 3072 + d;
#pragma unroll
  for (int k = 0; k < 4; ++k) {
    int tt = t + k - 3;
    if (tt >= 0) acc = fmaf(base[(ptrdiff_t)(k - 3) * 3072], wv[k], acc);
  }
  xc[idx] = acc / (1.f + __expf(-acc));   // silu
}

// ---------------- K4: x_ssm = xc @ w_x -> Bm(.,16) Cm(.,16) dtr(.) ---------
// one wave per (b,t) row; K=1536, 33 outputs
__global__ __launch_bounds__(256) void xssm_k(const float* __restrict__ xc,
                                              const float* __restrict__ wx,
                                              float* __restrict__ Bm,
                                              float* __restrict__ Cm,
                                              float* __restrict__ dtr) {
  int wv = threadIdx.x >> 6, lane = threadIdx.x & 63;
  int row = blockIdx.x * 4 + wv;           // grid=1024 -> 4096 rows
  const float* xr = xc + (size_t)row * DI;
  float acc[33];
#pragma unroll
  for (int j = 0; j < 33; ++j) acc[j] = 0.f;
  for (int k = lane; k < DI; k += 64) {
    float xv = xr[k];
    const float* wr = wx + (size_t)k * 33;
#pragma unroll
    for (int j = 0; j < 33; ++j) acc[j] = fmaf(xv, wr[j], acc[j]);
  }
#pragma unroll
  for (int j = 0; j < 33; ++j) {
#pragma unroll
    for (int off = 32; off >= 1; off >>= 1) acc[j] += __shfl_xor(acc[j], off, 64);
  }
  if (lane == 0) {
#pragma unroll
    for (int j = 0; j < 16; ++j) Bm[(size_t)row * 16 + j] = acc[j];
#pragma unroll
    for (int j = 0; j < 16; ++j) Cm[(size_t)row * 16 + j] = acc[16 + j];
    dtr[row] = acc[32];
  }
}

// ---------------- K5: sequential selective scan + fused epilogue -----------
// block = 16 d-channels x 16 states; lane n holds h[n]; y via 4 shfl_xor.
// writes yfinal into xz cols 0..1535 (x_main columns are dead after conv).
__global__ __launch_bounds__(256) void scan_k(
    const float* __restrict__ xc,
    float* __restrict__ xz,          // read z at cols 1536.., write y at cols 0..
    const float* __restrict__ Bm, const float* __restrict__ Cm,
    const float* __restrict__ dtr,
    const float* __restrict__ w_dt, const float* __restrict__ b_dt,
    const float* __restrict__ A_log, const float* __restrict__ Dp) {
  const int b = blockIdx.x / (DI / 16);
  const int d0 = (blockIdx.x % (DI / 16)) * 16;
  const int tid = threadIdx.x;
  const int n = tid & 15;
  const int di = tid >> 4;
  const int d = d0 + di;

  __shared__ float sB[128][16], sC[128][16], sx[128][16], sdt[128];

  const float wdt = w_dt[d];
  const float bdt = b_dt[d];
  const float a = -expf(A_log[d * DS2 + n]);
  const float Dd = Dp[d];
  float h = 0.f;

  for (int c = 0; c < SEQN / 128; ++c) {
    const size_t cb = (size_t)b * SEQN + c * 128;  // row base of chunk
    __syncthreads();
#pragma unroll
    for (int r = 0; r < 2; ++r) {          // B,C chunks: 2048 contiguous floats
      int f4 = tid + r * 256;
      reinterpret_cast<float4*>(&sB[0][0])[f4] = reinterpret_cast<const float4*>(&Bm[cb * 16])[f4];
      reinterpret_cast<float4*>(&sC[0][0])[f4] = reinterpret_cast<const float4*>(&Cm[cb * 16])[f4];
    }
#pragma unroll
    for (int r = 0; r < 8; ++r) {          // x chunk: rows of 16 at stride DI
      int idx = tid + r * 256;
      int tt = idx >> 4, dd = idx & 15;
      sx[tt][dd] = xc[(cb + tt) * DI + d0 + dd];
    }
    if (tid < 128) sdt[tid] = dtr[cb + tid];
    __syncthreads();
#pragma unroll 4
    for (int tt = 0; tt < 128; ++tt) {
      float v = fmaf(sdt[tt], wdt, bdt);
      float dt = (v > 15.f) ? v : __logf(1.f + __expf(v));  // softplus
      float xv = sx[tt][di];
      float p = __expf(a * dt);
      h = fmaf(p, h, dt * xv * sB[tt][n]);
      float yv = h * sC[tt][n];
      yv += __shfl_xor(yv, 1, 64);
      yv += __shfl_xor(yv, 2, 64);
      yv += __shfl_xor(yv, 4, 64);
      yv += __shfl_xor(yv, 8, 64);
      if (n == 0) {
        size_t rr = cb + tt;
        float z = xz[rr * 3072 + DI + d];
        float yo = fmaf(xv, Dd, yv);
        xz[rr * 3072 + d] = yo * (z / (1.f + __expf(-z)));
      }
    }
  }
}

// ---------------- launcher -------------------------------------------------
extern "C" void kernel_launch(void* const* d_in, const int* in_sizes, int n_in,
                              void* d_out, int out_size, void* d_ws, size_t ws_size,
                              hipStream_t stream) {
  const float* x      = (const float*)d_in[0];
  const float* norm_w = (const float*)d_in[1];
  const float* w_in   = (const float*)d_in[2];
  const float* conv_w = (const float*)d_in[3];
  const float* conv_b = (const float*)d_in[4];
  const float* w_x    = (const float*)d_in[5];
  const float* w_dt   = (const float*)d_in[6];
  const float* b_dt   = (const float*)d_in[7];
  const float* A_log  = (const float*)d_in[8];
  const float* Dp     = (const float*)d_in[9];
  const float* w_out  = (const float*)d_in[10];
  float* out = (float*)d_out;

  // workspace layout (floats): xz(12.58M) xc(6.29M) Bm(64K) Cm(64K) dtr(4K) rinv(4K)
  float* ws   = (float*)d_ws;
  float* xz   = ws;                          // 4096 x 3072
  float* xc   = xz + (size_t)NROWS * 2 * DI; // 4096 x 1536
  float* Bm   = xc + (size_t)NROWS * DI;     // 4096 x 16
  float* Cm   = Bm + (size_t)NROWS * 16;     // 4096 x 16
  float* dtr  = Cm + (size_t)NROWS * 16;     // 4096
  float* rinv = dtr + NROWS;                 // 4096
  // total ~76 MB

  // 1. rmsnorm row scales
  rms_k<<<NROWS / 4, 256, 0, stream>>>(x, rinv);
  // 2. xz = (rinv * x * norm_w) @ w_in     M=4096 K=768 N=3072
  gemm_f32<<<dim3(2 * DI / 128, NROWS / 128), 256, 0, stream>>>(
      x, DM, w_in, 2 * DI, xz, 2 * DI, DM, rinv, norm_w, nullptr, 0);
  // 3. xc = silu(causal_conv(xz[:, :1536]) + conv_b)
  conv_silu_k<<<(NROWS * DI) / 256, 256, 0, stream>>>(xz, conv_w, conv_b, xc);
  // 4. B, C, dt_raw = xc @ w_x
  xssm_k<<<NROWS / 4, 256, 0, stream>>>(xc, w_x, Bm, Cm, dtr);
  // 5. selective scan + (y + x*D)*silu(z), y -> xz cols 0..1535
  scan_k<<<BSZ * (DI / 16), 256, 0, stream>>>(xc, xz, Bm, Cm, dtr, w_dt, b_dt, A_log, Dp);
  // 6. out = x + y @ w_out                 M=4096 K=1536 N=768
  gemm_f32<<<dim3(DM / 128, NROWS / 128), 256, 0, stream>>>(
      xz, 2 * DI, w_out, DM, out, DM, DI, nullptr, nullptr, x, DM);
}

// Round 2
// 873.347 us; speedup vs baseline: 2.0724x; 2.0724x over previous
//
#include <hip/hip_runtime.h>
#include <math.h>

// S6 (Mamba-style) block, B=2 S=2048 Dm=768 Di=1536 Ds=16 K=4, all f32.
// Round 2: chunked parallel scan (16 chunks x 128) replaces serial scan_k.
//          Everything else identical to Round 1. Next lever: bf16 MFMA GEMMs.

#define DM   768
#define DI   1536
#define DS2  16
#define SEQN 2048
#define BSZ  2
#define NROWS (BSZ*SEQN)   // 4096
#define CHUNK 128
#define NCHUNK (SEQN/CHUNK) // 16

// ---------------- K1: per-row inverse RMS of x ----------------
__global__ __launch_bounds__(256) void rms_k(const float* __restrict__ x,
                                             float* __restrict__ rinv) {
  int wv = threadIdx.x >> 6, lane = threadIdx.x & 63;
  int row = blockIdx.x * 4 + wv;            // 4096 rows, grid=1024
  const float* xr = x + (size_t)row * DM;
  float s = 0.f;
#pragma unroll
  for (int i = 0; i < DM / 64; ++i) { float v = xr[lane + i * 64]; s = fmaf(v, v, s); }
#pragma unroll
  for (int off = 32; off >= 1; off >>= 1) s += __shfl_xor(s, off, 64);
  if (lane == 0) rinv[row] = rsqrtf(s * (1.f / DM) + 1e-6f);
}

// ---------------- generic f32 GEMM: C = [res +] (rowscale*colscale*A) @ B ---
__global__ __launch_bounds__(256) void gemm_f32(
    const float* __restrict__ A, int lda,
    const float* __restrict__ B, int ldb,
    float* __restrict__ C, int ldc, int K,
    const float* __restrict__ rowscale,
    const float* __restrict__ colscale,
    const float* __restrict__ res, int ldr)
{
  __shared__ float As[16][130];
  __shared__ float Bs[16][128];
  const int tid = threadIdx.x;
  const int m0 = blockIdx.y * 128, n0 = blockIdx.x * 128;
  const int tx = tid & 15, ty = tid >> 4;
  float acc[8][8];
#pragma unroll
  for (int i = 0; i < 8; ++i)
#pragma unroll
    for (int j = 0; j < 8; ++j) acc[i][j] = 0.f;

  for (int k0 = 0; k0 < K; k0 += 16) {
    __syncthreads();
#pragma unroll
    for (int r = 0; r < 2; ++r) {
      int idx = tid + r * 256;
      int row = idx >> 2;
      int kq = (idx & 3) << 2;
      float4 v = *reinterpret_cast<const float4*>(&A[(size_t)(m0 + row) * lda + k0 + kq]);
      if (rowscale) { float rs = rowscale[m0 + row]; v.x *= rs; v.y *= rs; v.z *= rs; v.w *= rs; }
      if (colscale) {
        const float4 cs = *reinterpret_cast<const float4*>(&colscale[k0 + kq]);
        v.x *= cs.x; v.y *= cs.y; v.z *= cs.z; v.w *= cs.w;
      }
      As[kq + 0][row] = v.x; As[kq + 1][row] = v.y;
      As[kq + 2][row] = v.z; As[kq + 3][row] = v.w;
    }
#pragma unroll
    for (int r = 0; r < 2; ++r) {
      int idx = tid + r * 256;
      int row = idx >> 5;
      int nq = (idx & 31) << 2;
      *reinterpret_cast<float4*>(&Bs[row][nq]) =
          *reinterpret_cast<const float4*>(&B[(size_t)(k0 + row) * ldb + n0 + nq]);
    }
    __syncthreads();
#pragma unroll
    for (int k = 0; k < 16; ++k) {
      float av[8], bv[8];
#pragma unroll
      for (int i = 0; i < 8; ++i) av[i] = As[k][ty * 8 + i];
#pragma unroll
      for (int j = 0; j < 8; ++j) bv[j] = Bs[k][tx + j * 16];
#pragma unroll
      for (int i = 0; i < 8; ++i)
#pragma unroll
        for (int j = 0; j < 8; ++j) acc[i][j] = fmaf(av[i], bv[j], acc[i][j]);
    }
  }
#pragma unroll
  for (int i = 0; i < 8; ++i) {
    int m = m0 + ty * 8 + i;
#pragma unroll
    for (int j = 0; j < 8; ++j) {
      int n = n0 + tx + j * 16;
      float v = acc[i][j];
      if (res) v += res[(size_t)m * ldr + n];
      C[(size_t)m * ldc + n] = v;
    }
  }
}

// ---------------- K3: depthwise causal conv(K=4) + bias + SiLU -------------
__global__ __launch_bounds__(256) void conv_silu_k(const float* __restrict__ xz,
                                                   const float* __restrict__ cw,
                                                   const float* __restrict__ cb,
                                                   float* __restrict__ xc) {
  int idx = blockIdx.x * 256 + threadIdx.x;
  int d = idx % DI;
  int bt = idx / DI;
  int t = bt & (SEQN - 1);
  float acc = cb[d];
  const float4 w4 = *reinterpret_cast<const float4*>(&cw[d * 4]);
  const float wv[4] = {w4.x, w4.y, w4.z, w4.w};
  const float* base = xz + (size_t)bt * 3072 + d;
#pragma unroll
  for (int k = 0; k < 4; ++k) {
    int tt = t + k - 3;
    if (tt >= 0) acc = fmaf(base[(ptrdiff_t)(k - 3) * 3072], wv[k], acc);
  }
  xc[idx] = acc / (1.f + __expf(-acc));
}

// ---------------- K4: x_ssm = xc @ w_x -> Bm(.,16) Cm(.,16) dtr(.) ---------
__global__ __launch_bounds__(256) void xssm_k(const float* __restrict__ xc,
                                              const float* __restrict__ wx,
                                              float* __restrict__ Bm,
                                              float* __restrict__ Cm,
                                              float* __restrict__ dtr) {
  int wv = threadIdx.x >> 6, lane = threadIdx.x & 63;
  int row = blockIdx.x * 4 + wv;
  const float* xr = xc + (size_t)row * DI;
  float acc[33];
#pragma unroll
  for (int j = 0; j < 33; ++j) acc[j] = 0.f;
  for (int k = lane; k < DI; k += 64) {
    float xv = xr[k];
    const float* wr = wx + (size_t)k * 33;
#pragma unroll
    for (int j = 0; j < 33; ++j) acc[j] = fmaf(xv, wr[j], acc[j]);
  }
#pragma unroll
  for (int j = 0; j < 33; ++j) {
#pragma unroll
    for (int off = 32; off >= 1; off >>= 1) acc[j] += __shfl_xor(acc[j], off, 64);
  }
  if (lane == 0) {
#pragma unroll
    for (int j = 0; j < 16; ++j) Bm[(size_t)row * 16 + j] = acc[j];
#pragma unroll
    for (int j = 0; j < 16; ++j) Cm[(size_t)row * 16 + j] = acc[16 + j];
    dtr[row] = acc[32];
  }
}

// ---------------- K5a: per-chunk local scan (h0=0) -> hL, Tsum -------------
// grid: B * (DI/16) * NCHUNK blocks; block = 16d x 16n.
// blockIdx.x = ((b*(DI/16) + db) * NCHUNK + c)
__global__ __launch_bounds__(256) void scan_part1(
    const float* __restrict__ xc,
    const float* __restrict__ Bm, const float* __restrict__ dtr,
    const float* __restrict__ w_dt, const float* __restrict__ b_dt,
    const float* __restrict__ A_log,
    float* __restrict__ hL,     // [B][NCHUNK][DI][16]
    float* __restrict__ Tsum)   // [B][NCHUNK][DI]
{
  const int blk = blockIdx.x;
  const int c  = blk % NCHUNK;
  const int db = (blk / NCHUNK) % (DI / 16);
  const int b  = blk / (NCHUNK * (DI / 16));
  const int d0 = db * 16;
  const int tid = threadIdx.x;
  const int n = tid & 15, di = tid >> 4, d = d0 + di;

  __shared__ float sB[CHUNK][16], sx[CHUNK][16], sdt[CHUNK];
  const size_t cb = (size_t)b * SEQN + c * CHUNK;
#pragma unroll
  for (int r = 0; r < 2; ++r) {
    int f4 = tid + r * 256;
    reinterpret_cast<float4*>(&sB[0][0])[f4] =
        reinterpret_cast<const float4*>(&Bm[cb * 16])[f4];
  }
#pragma unroll
  for (int r = 0; r < 8; ++r) {
    int idx = tid + r * 256;
    int tt = idx >> 4, dd = idx & 15;
    sx[tt][dd] = xc[(cb + tt) * DI + d0 + dd];
  }
  if (tid < CHUNK) sdt[tid] = dtr[cb + tid];
  __syncthreads();

  const float wdt = w_dt[d], bdt = b_dt[d];
  const float a = -expf(A_log[d * DS2 + n]);
  float h = 0.f, T = 0.f;
#pragma unroll 4
  for (int tt = 0; tt < CHUNK; ++tt) {
    float v = fmaf(sdt[tt], wdt, bdt);
    float dt = (v > 15.f) ? v : __logf(1.f + __expf(v));
    float p = __expf(a * dt);
    h = fmaf(p, h, dt * sx[tt][di] * sB[tt][n]);
    T += dt;
  }
  hL[((size_t)(b * NCHUNK + c) * DI + d) * 16 + n] = h;
  if (n == 0) Tsum[(size_t)(b * NCHUNK + c) * DI + d] = T;
}

// ---------------- K5b: replay chunk with true h_init + fused epilogue ------
__global__ __launch_bounds__(256) void scan_part3(
    const float* __restrict__ xc,
    float* __restrict__ xz,          // read z at cols 1536.., write y at cols 0..
    const float* __restrict__ Bm, const float* __restrict__ Cm,
    const float* __restrict__ dtr,
    const float* __restrict__ w_dt, const float* __restrict__ b_dt,
    const float* __restrict__ A_log, const float* __restrict__ Dp,
    const float* __restrict__ hL, const float* __restrict__ Tsum)
{
  const int blk = blockIdx.x;
  const int c  = blk % NCHUNK;
  const int db = (blk / NCHUNK) % (DI / 16);
  const int b  = blk / (NCHUNK * (DI / 16));
  const int d0 = db * 16;
  const int tid = threadIdx.x;
  const int n = tid & 15, di = tid >> 4, d = d0 + di;

  __shared__ float sB[CHUNK][16], sC[CHUNK][16], sx[CHUNK][16], sdt[CHUNK];
  const size_t cb = (size_t)b * SEQN + c * CHUNK;
#pragma unroll
  for (int r = 0; r < 2; ++r) {
    int f4 = tid + r * 256;
    reinterpret_cast<float4*>(&sB[0][0])[f4] =
        reinterpret_cast<const float4*>(&Bm[cb * 16])[f4];
    reinterpret_cast<float4*>(&sC[0][0])[f4] =
        reinterpret_cast<const float4*>(&Cm[cb * 16])[f4];
  }
#pragma unroll
  for (int r = 0; r < 8; ++r) {
    int idx = tid + r * 256;
    int tt = idx >> 4, dd = idx & 15;
    sx[tt][dd] = xc[(cb + tt) * DI + d0 + dd];
  }
  if (tid < CHUNK) sdt[tid] = dtr[cb + tid];

  const float wdt = w_dt[d], bdt = b_dt[d];
  const float a = -expf(A_log[d * DS2 + n]);
  const float Dd = Dp[d];

  // inline chunk-combine: h_init = H[c-1], H[cp] = exp(a*T[cp])*H[cp-1]+hL[cp]
  float h = 0.f;
  for (int cp = 0; cp < c; ++cp) {
    float T = Tsum[(size_t)(b * NCHUNK + cp) * DI + d];
    float hl = hL[((size_t)(b * NCHUNK + cp) * DI + d) * 16 + n];
    h = fmaf(__expf(a * T), h, hl);
  }
  __syncthreads();

#pragma unroll 4
  for (int tt = 0; tt < CHUNK; ++tt) {
    float v = fmaf(sdt[tt], wdt, bdt);
    float dt = (v > 15.f) ? v : __logf(1.f + __expf(v));
    float xv = sx[tt][di];
    float p = __expf(a * dt);
    h = fmaf(p, h, dt * xv * sB[tt][n]);
    float yv = h * sC[tt][n];
    yv += __shfl_xor(yv, 1, 64);
    yv += __shfl_xor(yv, 2, 64);
    yv += __shfl_xor(yv, 4, 64);
    yv += __shfl_xor(yv, 8, 64);
    if (n == 0) {
      size_t rr = cb + tt;
      float z = xz[rr * 3072 + DI + d];
      float yo = fmaf(xv, Dd, yv);
      xz[rr * 3072 + d] = yo * (z / (1.f + __expf(-z)));
    }
  }
}

// ---------------- launcher -------------------------------------------------
extern "C" void kernel_launch(void* const* d_in, const int* in_sizes, int n_in,
                              void* d_out, int out_size, void* d_ws, size_t ws_size,
                              hipStream_t stream) {
  const float* x      = (const float*)d_in[0];
  const float* norm_w = (const float*)d_in[1];
  const float* w_in   = (const float*)d_in[2];
  const float* conv_w = (const float*)d_in[3];
  const float* conv_b = (const float*)d_in[4];
  const float* w_x    = (const float*)d_in[5];
  const float* w_dt   = (const float*)d_in[6];
  const float* b_dt   = (const float*)d_in[7];
  const float* A_log  = (const float*)d_in[8];
  const float* Dp     = (const float*)d_in[9];
  const float* w_out  = (const float*)d_in[10];
  float* out = (float*)d_out;

  // workspace layout (floats):
  float* ws   = (float*)d_ws;
  float* xz   = ws;                          // 4096 x 3072
  float* xc   = xz + (size_t)NROWS * 2 * DI; // 4096 x 1536
  float* Bm   = xc + (size_t)NROWS * DI;     // 4096 x 16
  float* Cm   = Bm + (size_t)NROWS * 16;     // 4096 x 16
  float* dtr  = Cm + (size_t)NROWS * 16;     // 4096
  float* rinv = dtr + NROWS;                 // 4096
  float* hL   = rinv + NROWS;                // B*NCHUNK*DI*16 = 786432
  float* Tsum = hL + (size_t)BSZ * NCHUNK * DI * 16;  // 49152
  // total ~80 MB

  rms_k<<<NROWS / 4, 256, 0, stream>>>(x, rinv);
  gemm_f32<<<dim3(2 * DI / 128, NROWS / 128), 256, 0, stream>>>(
      x, DM, w_in, 2 * DI, xz, 2 * DI, DM, rinv, norm_w, nullptr, 0);
  conv_silu_k<<<(NROWS * DI) / 256, 256, 0, stream>>>(xz, conv_w, conv_b, xc);
  xssm_k<<<NROWS / 4, 256, 0, stream>>>(xc, w_x, Bm, Cm, dtr);

  const int nblk = BSZ * (DI / 16) * NCHUNK;  // 3072
  scan_part1<<<nblk, 256, 0, stream>>>(xc, Bm, dtr, w_dt, b_dt, A_log, hL, Tsum);
  scan_part3<<<nblk, 256, 0, stream>>>(xc, xz, Bm, Cm, dtr, w_dt, b_dt, A_log, Dp, hL, Tsum);

  gemm_f32<<<dim3(DM / 128, NROWS / 128), 256, 0, stream>>>(
      xz, 2 * DI, w_out, DM, out, DM, DI, nullptr, nullptr, x, DM);
}

// Round 3
// 472.671 us; speedup vs baseline: 3.8292x; 1.8477x over previous
//
#include <hip/hip_runtime.h>
#include <math.h>

// S6 (Mamba-style) block, B=2 S=2048 Dm=768 Di=1536 Ds=16 K=4.
// Round 3: both GEMMs -> bf16 MFMA (m97 structure: 128x128 tile, BK=64,
//          global_load_lds width-16, 4 waves x 4x4 16x16x32 frags).
//          Scan/conv/xssm unchanged from Round 2.

#define DM   768
#define DI   1536
#define DS2  16
#define SEQN 2048
#define BSZ  2
#define NROWS (BSZ*SEQN)   // 4096
#define CHUNK 128
#define NCHUNK (SEQN/CHUNK) // 16

#define AS1 __attribute__((address_space(1)))
#define AS3 __attribute__((address_space(3)))

typedef short short8 __attribute__((ext_vector_type(8)));
typedef short short4v __attribute__((ext_vector_type(4)));
typedef float f32x4 __attribute__((ext_vector_type(4)));

__device__ __forceinline__ unsigned short f2bf(float f) {
  unsigned u = __builtin_bit_cast(unsigned, f);
  unsigned r = (u + 0x7FFFu + ((u >> 16) & 1u)) >> 16;   // RTNE
  return (unsigned short)r;
}

// ---------------- K1: per-row inverse RMS of x ----------------
__global__ __launch_bounds__(256) void rms_k(const float* __restrict__ x,
                                             float* __restrict__ rinv) {
  int wv = threadIdx.x >> 6, lane = threadIdx.x & 63;
  int row = blockIdx.x * 4 + wv;
  const float* xr = x + (size_t)row * DM;
  float s = 0.f;
#pragma unroll
  for (int i = 0; i < DM / 64; ++i) { float v = xr[lane + i * 64]; s = fmaf(v, v, s); }
#pragma unroll
  for (int off = 32; off >= 1; off >>= 1) s += __shfl_xor(s, off, 64);
  if (lane == 0) rinv[row] = rsqrtf(s * (1.f / DM) + 1e-6f);
}

// ---------------- K1b: xn_bf16 = bf16(x * rinv * norm_w) -------------------
__global__ __launch_bounds__(256) void cvt_xn_k(const float* __restrict__ x,
                                                const float* __restrict__ rinv,
                                                const float* __restrict__ nw,
                                                short* __restrict__ xn) {
  int idx = blockIdx.x * 256 + threadIdx.x;     // one float4 each
  int row = idx / (DM / 4);
  int c4 = (idx % (DM / 4)) * 4;
  float rs = rinv[row];
  float4 v = *reinterpret_cast<const float4*>(&x[(size_t)row * DM + c4]);
  float4 w = *reinterpret_cast<const float4*>(&nw[c4]);
  short4v o;
  o.x = (short)f2bf(v.x * rs * w.x); o.y = (short)f2bf(v.y * rs * w.y);
  o.z = (short)f2bf(v.z * rs * w.z); o.w = (short)f2bf(v.w * rs * w.w);
  *reinterpret_cast<short4v*>(&xn[(size_t)row * DM + c4]) = o;
}

// ---------------- K1c: dst[c][r] = bf16(src[r][c]) (tiled transpose) -------
__global__ __launch_bounds__(256) void cvt_transpose_k(const float* __restrict__ src,
                                                       int rows, int cols,
                                                       short* __restrict__ dst) {
  __shared__ float t[32][33];
  int r0 = blockIdx.y * 32, c0 = blockIdx.x * 32;
  int tid = threadIdx.x;
  int lr = tid >> 3, lc4 = (tid & 7) * 4;
  float4 v = *reinterpret_cast<const float4*>(&src[(size_t)(r0 + lr) * cols + c0 + lc4]);
  t[lr][lc4 + 0] = v.x; t[lr][lc4 + 1] = v.y; t[lr][lc4 + 2] = v.z; t[lr][lc4 + 3] = v.w;
  __syncthreads();
  int orow = tid >> 3, oc4 = (tid & 7) * 4;    // dst row c0+orow, cols r0+oc4..
  short4v o;
  o.x = (short)f2bf(t[oc4 + 0][orow]); o.y = (short)f2bf(t[oc4 + 1][orow]);
  o.z = (short)f2bf(t[oc4 + 2][orow]); o.w = (short)f2bf(t[oc4 + 3][orow]);
  *reinterpret_cast<short4v*>(&dst[(size_t)(c0 + orow) * rows + r0 + oc4]) = o;
}

// ---------------- bf16 MFMA GEMM: C = [res +] A @ B^T ----------------------
// A: [M][K] bf16 (lda=K), Bt: [N][K] bf16 (ldb=K), C: [M][N] f32.
// 128x128 tile, BK=64, 256 thr = 4 waves (2x2), each wave 64x64 out.
__global__ __launch_bounds__(256) void gemm_bf16(
    const short* __restrict__ A, int lda,
    const short* __restrict__ Bt, int ldb,
    float* __restrict__ C, int ldc, int K,
    const float* __restrict__ res, int ldr)
{
  __shared__ __align__(16) short As[128 * 64];
  __shared__ __align__(16) short Bs[128 * 64];
  const int tid = threadIdx.x;
  const int w = tid >> 6, lane = tid & 63;
  const int wr = w >> 1, wc = w & 1;
  const int m0 = blockIdx.y * 128, n0 = blockIdx.x * 128;
  const int l15 = lane & 15, l4 = lane >> 4;

  f32x4 acc[4][4];
#pragma unroll
  for (int i = 0; i < 4; ++i)
#pragma unroll
    for (int j = 0; j < 4; ++j) acc[i][j] = (f32x4){0.f, 0.f, 0.f, 0.f};

  const int srow = (lane >> 3);          // staging: row within 8-row chunk
  const int skb = (lane & 7) * 8;        // k element offset (16B per lane)

  for (int k0 = 0; k0 < K; k0 += 64) {
    __syncthreads();
#pragma unroll
    for (int q = 0; q < 4; ++q) {
      int c = w * 4 + q;                 // chunk 0..15 -> rows 8c..8c+7
      int row = 8 * c + srow;
      __builtin_amdgcn_global_load_lds(
          (const AS1 unsigned int*)(A + (size_t)(m0 + row) * lda + k0 + skb),
          (AS3 unsigned int*)((char*)As + c * 1024), 16, 0, 0);
      __builtin_amdgcn_global_load_lds(
          (const AS1 unsigned int*)(Bt + (size_t)(n0 + row) * ldb + k0 + skb),
          (AS3 unsigned int*)((char*)Bs + c * 1024), 16, 0, 0);
    }
    __syncthreads();
#pragma unroll
    for (int kk = 0; kk < 2; ++kk) {
      short8 a[4], b[4];
#pragma unroll
      for (int i = 0; i < 4; ++i)
        a[i] = *reinterpret_cast<const short8*>(
            &As[(wr * 64 + i * 16 + l15) * 64 + kk * 32 + l4 * 8]);
#pragma unroll
      for (int j = 0; j < 4; ++j)
        b[j] = *reinterpret_cast<const short8*>(
            &Bs[(wc * 64 + j * 16 + l15) * 64 + kk * 32 + l4 * 8]);
#pragma unroll
      for (int i = 0; i < 4; ++i)
#pragma unroll
        for (int j = 0; j < 4; ++j)
          acc[i][j] = __builtin_amdgcn_mfma_f32_16x16x32_bf16(a[i], b[j], acc[i][j], 0, 0, 0);
    }
  }

#pragma unroll
  for (int i = 0; i < 4; ++i) {
#pragma unroll
    for (int j = 0; j < 4; ++j) {
      int col = n0 + wc * 64 + j * 16 + l15;
#pragma unroll
      for (int r = 0; r < 4; ++r) {
        int row = m0 + wr * 64 + i * 16 + l4 * 4 + r;
        float v = acc[i][j][r];
        if (res) v += res[(size_t)row * ldr + col];
        C[(size_t)row * ldc + col] = v;
      }
    }
  }
}

// ---------------- K3: depthwise causal conv(K=4) + bias + SiLU -------------
__global__ __launch_bounds__(256) void conv_silu_k(const float* __restrict__ xz,
                                                   const float* __restrict__ cw,
                                                   const float* __restrict__ cb,
                                                   float* __restrict__ xc) {
  int idx = blockIdx.x * 256 + threadIdx.x;
  int d = idx % DI;
  int bt = idx / DI;
  int t = bt & (SEQN - 1);
  float acc = cb[d];
  const float4 w4 = *reinterpret_cast<const float4*>(&cw[d * 4]);
  const float wv[4] = {w4.x, w4.y, w4.z, w4.w};
  const float* base = xz + (size_t)bt * 3072 + d;
#pragma unroll
  for (int k = 0; k < 4; ++k) {
    int tt = t + k - 3;
    if (tt >= 0) acc = fmaf(base[(ptrdiff_t)(k - 3) * 3072], wv[k], acc);
  }
  xc[idx] = acc / (1.f + __expf(-acc));
}

// ---------------- K4: x_ssm = xc @ w_x -> Bm(.,16) Cm(.,16) dtr(.) ---------
__global__ __launch_bounds__(256) void xssm_k(const float* __restrict__ xc,
                                              const float* __restrict__ wx,
                                              float* __restrict__ Bm,
                                              float* __restrict__ Cm,
                                              float* __restrict__ dtr) {
  int wv = threadIdx.x >> 6, lane = threadIdx.x & 63;
  int row = blockIdx.x * 4 + wv;
  const float* xr = xc + (size_t)row * DI;
  float acc[33];
#pragma unroll
  for (int j = 0; j < 33; ++j) acc[j] = 0.f;
  for (int k = lane; k < DI; k += 64) {
    float xv = xr[k];
    const float* wr = wx + (size_t)k * 33;
#pragma unroll
    for (int j = 0; j < 33; ++j) acc[j] = fmaf(xv, wr[j], acc[j]);
  }
#pragma unroll
  for (int j = 0; j < 33; ++j) {
#pragma unroll
    for (int off = 32; off >= 1; off >>= 1) acc[j] += __shfl_xor(acc[j], off, 64);
  }
  if (lane == 0) {
#pragma unroll
    for (int j = 0; j < 16; ++j) Bm[(size_t)row * 16 + j] = acc[j];
#pragma unroll
    for (int j = 0; j < 16; ++j) Cm[(size_t)row * 16 + j] = acc[16 + j];
    dtr[row] = acc[32];
  }
}

// ---------------- K5a: per-chunk local scan (h0=0) -> hL, Tsum -------------
__global__ __launch_bounds__(256) void scan_part1(
    const float* __restrict__ xc,
    const float* __restrict__ Bm, const float* __restrict__ dtr,
    const float* __restrict__ w_dt, const float* __restrict__ b_dt,
    const float* __restrict__ A_log,
    float* __restrict__ hL, float* __restrict__ Tsum)
{
  const int blk = blockIdx.x;
  const int c  = blk % NCHUNK;
  const int db = (blk / NCHUNK) % (DI / 16);
  const int b  = blk / (NCHUNK * (DI / 16));
  const int d0 = db * 16;
  const int tid = threadIdx.x;
  const int n = tid & 15, di = tid >> 4, d = d0 + di;

  __shared__ float sB[CHUNK][16], sx[CHUNK][16], sdt[CHUNK];
  const size_t cb = (size_t)b * SEQN + c * CHUNK;
#pragma unroll
  for (int r = 0; r < 2; ++r) {
    int f4 = tid + r * 256;
    reinterpret_cast<float4*>(&sB[0][0])[f4] =
        reinterpret_cast<const float4*>(&Bm[cb * 16])[f4];
  }
#pragma unroll
  for (int r = 0; r < 8; ++r) {
    int idx = tid + r * 256;
    int tt = idx >> 4, dd = idx & 15;
    sx[tt][dd] = xc[(cb + tt) * DI + d0 + dd];
  }
  if (tid < CHUNK) sdt[tid] = dtr[cb + tid];
  __syncthreads();

  const float wdt = w_dt[d], bdt = b_dt[d];
  const float a = -expf(A_log[d * DS2 + n]);
  float h = 0.f, T = 0.f;
#pragma unroll 4
  for (int tt = 0; tt < CHUNK; ++tt) {
    float v = fmaf(sdt[tt], wdt, bdt);
    float dt = (v > 15.f) ? v : __logf(1.f + __expf(v));
    float p = __expf(a * dt);
    h = fmaf(p, h, dt * sx[tt][di] * sB[tt][n]);
    T += dt;
  }
  hL[((size_t)(b * NCHUNK + c) * DI + d) * 16 + n] = h;
  if (n == 0) Tsum[(size_t)(b * NCHUNK + c) * DI + d] = T;
}

// ---------------- K5b: replay chunk with true h_init + fused epilogue ------
// writes y_final as bf16 into ybf (GEMM3's A operand)
__global__ __launch_bounds__(256) void scan_part3(
    const float* __restrict__ xc,
    const float* __restrict__ xz,    // read z at cols 1536..
    short* __restrict__ ybf,
    const float* __restrict__ Bm, const float* __restrict__ Cm,
    const float* __restrict__ dtr,
    const float* __restrict__ w_dt, const float* __restrict__ b_dt,
    const float* __restrict__ A_log, const float* __restrict__ Dp,
    const float* __restrict__ hL, const float* __restrict__ Tsum)
{
  const int blk = blockIdx.x;
  const int c  = blk % NCHUNK;
  const int db = (blk / NCHUNK) % (DI / 16);
  const int b  = blk / (NCHUNK * (DI / 16));
  const int d0 = db * 16;
  const int tid = threadIdx.x;
  const int n = tid & 15, di = tid >> 4, d = d0 + di;

  __shared__ float sB[CHUNK][16], sC[CHUNK][16], sx[CHUNK][16], sdt[CHUNK];
  const size_t cb = (size_t)b * SEQN + c * CHUNK;
#pragma unroll
  for (int r = 0; r < 2; ++r) {
    int f4 = tid + r * 256;
    reinterpret_cast<float4*>(&sB[0][0])[f4] =
        reinterpret_cast<const float4*>(&Bm[cb * 16])[f4];
    reinterpret_cast<float4*>(&sC[0][0])[f4] =
        reinterpret_cast<const float4*>(&Cm[cb * 16])[f4];
  }
#pragma unroll
  for (int r = 0; r < 8; ++r) {
    int idx = tid + r * 256;
    int tt = idx >> 4, dd = idx & 15;
    sx[tt][dd] = xc[(cb + tt) * DI + d0 + dd];
  }
  if (tid < CHUNK) sdt[tid] = dtr[cb + tid];

  const float wdt = w_dt[d], bdt = b_dt[d];
  const float a = -expf(A_log[d * DS2 + n]);
  const float Dd = Dp[d];

  float h = 0.f;
  for (int cp = 0; cp < c; ++cp) {
    float T = Tsum[(size_t)(b * NCHUNK + cp) * DI + d];
    float hl = hL[((size_t)(b * NCHUNK + cp) * DI + d) * 16 + n];
    h = fmaf(__expf(a * T), h, hl);
  }
  __syncthreads();

#pragma unroll 4
  for (int tt = 0; tt < CHUNK; ++tt) {
    float v = fmaf(sdt[tt], wdt, bdt);
    float dt = (v > 15.f) ? v : __logf(1.f + __expf(v));
    float xv = sx[tt][di];
    float p = __expf(a * dt);
    h = fmaf(p, h, dt * xv * sB[tt][n]);
    float yv = h * sC[tt][n];
    yv += __shfl_xor(yv, 1, 64);
    yv += __shfl_xor(yv, 2, 64);
    yv += __shfl_xor(yv, 4, 64);
    yv += __shfl_xor(yv, 8, 64);
    if (n == 0) {
      size_t rr = cb + tt;
      float z = xz[rr * 3072 + DI + d];
      float yo = fmaf(xv, Dd, yv);
      ybf[rr * DI + d] = (short)f2bf(yo * (z / (1.f + __expf(-z))));
    }
  }
}

// ---------------- launcher -------------------------------------------------
extern "C" void kernel_launch(void* const* d_in, const int* in_sizes, int n_in,
                              void* d_out, int out_size, void* d_ws, size_t ws_size,
                              hipStream_t stream) {
  const float* x      = (const float*)d_in[0];
  const float* norm_w = (const float*)d_in[1];
  const float* w_in   = (const float*)d_in[2];
  const float* conv_w = (const float*)d_in[3];
  const float* conv_b = (const float*)d_in[4];
  const float* w_x    = (const float*)d_in[5];
  const float* w_dt   = (const float*)d_in[6];
  const float* b_dt   = (const float*)d_in[7];
  const float* A_log  = (const float*)d_in[8];
  const float* Dp     = (const float*)d_in[9];
  const float* w_out  = (const float*)d_in[10];
  float* out = (float*)d_out;

  // workspace layout (float units)
  float* ws   = (float*)d_ws;
  float* xz   = ws;                          // 4096 x 3072 f32
  float* xc   = xz + (size_t)NROWS * 2 * DI; // 4096 x 1536 f32
  float* Bm   = xc + (size_t)NROWS * DI;     // 4096 x 16
  float* Cm   = Bm + (size_t)NROWS * 16;
  float* dtr  = Cm + (size_t)NROWS * 16;     // 4096
  float* rinv = dtr + NROWS;                 // 4096
  float* hL   = rinv + NROWS;                // 786432
  float* Tsum = hL + (size_t)BSZ * NCHUNK * DI * 16;  // 49152
  short* xnb  = (short*)(Tsum + (size_t)BSZ * NCHUNK * DI);  // 4096x768 bf16
  short* winT = xnb + (size_t)NROWS * DM;    // 3072x768 bf16
  short* woutT= winT + (size_t)2 * DI * DM;  // 768x1536 bf16
  short* ybf  = woutT + (size_t)DM * DI;     // 4096x1536 bf16
  // total ~106 MB

  rms_k<<<NROWS / 4, 256, 0, stream>>>(x, rinv);
  cvt_xn_k<<<(NROWS * DM / 4) / 256, 256, 0, stream>>>(x, rinv, norm_w, xnb);
  cvt_transpose_k<<<dim3(2 * DI / 32, DM / 32), 256, 0, stream>>>(w_in, DM, 2 * DI, winT);
  cvt_transpose_k<<<dim3(DM / 32, DI / 32), 256, 0, stream>>>(w_out, DI, DM, woutT);

  // GEMM1: xz = xn @ w_in   (M=4096 N=3072 K=768)
  gemm_bf16<<<dim3(2 * DI / 128, NROWS / 128), 256, 0, stream>>>(
      xnb, DM, winT, DM, xz, 2 * DI, DM, nullptr, 0);

  conv_silu_k<<<(NROWS * DI) / 256, 256, 0, stream>>>(xz, conv_w, conv_b, xc);
  xssm_k<<<NROWS / 4, 256, 0, stream>>>(xc, w_x, Bm, Cm, dtr);

  const int nblk = BSZ * (DI / 16) * NCHUNK;  // 3072
  scan_part1<<<nblk, 256, 0, stream>>>(xc, Bm, dtr, w_dt, b_dt, A_log, hL, Tsum);
  scan_part3<<<nblk, 256, 0, stream>>>(xc, xz, ybf, Bm, Cm, dtr, w_dt, b_dt, A_log, Dp, hL, Tsum);

  // GEMM3: out = x + y @ w_out   (M=4096 N=768 K=1536)
  gemm_bf16<<<dim3(DM / 128, NROWS / 128), 256, 0, stream>>>(
      ybf, DI, woutT, DI, out, DM, DI, x, DM);
}

// Round 4
// 301.990 us; speedup vs baseline: 5.9934x; 1.5652x over previous
//
#include <hip/hip_runtime.h>
#include <math.h>

// S6 (Mamba-style) block, B=2 S=2048 Dm=768 Di=1536 Ds=16 K=4.
// Round 4: scan re-parallelized — one thread owns one d-channel and all 16
//          states in registers (kills 16x redundant softplus, shfl chains,
//          and epilogue divergence). CHUNK=32/NCHUNK=64 + dedicated O(NC)
//          combine kernel (in-place hL -> Hinit). GEMMs/conv/xssm unchanged.

#define DM   768
#define DI   1536
#define DS2  16
#define SEQN 2048
#define BSZ  2
#define NROWS (BSZ*SEQN)   // 4096
#define CHUNK 32
#define NCHUNK (SEQN/CHUNK) // 64

#define AS1 __attribute__((address_space(1)))
#define AS3 __attribute__((address_space(3)))

typedef short short8 __attribute__((ext_vector_type(8)));
typedef short short4v __attribute__((ext_vector_type(4)));
typedef float f32x4 __attribute__((ext_vector_type(4)));

__device__ __forceinline__ unsigned short f2bf(float f) {
  unsigned u = __builtin_bit_cast(unsigned, f);
  unsigned r = (u + 0x7FFFu + ((u >> 16) & 1u)) >> 16;   // RTNE
  return (unsigned short)r;
}

// ---------------- K1: per-row inverse RMS of x ----------------
__global__ __launch_bounds__(256) void rms_k(const float* __restrict__ x,
                                             float* __restrict__ rinv) {
  int wv = threadIdx.x >> 6, lane = threadIdx.x & 63;
  int row = blockIdx.x * 4 + wv;
  const float* xr = x + (size_t)row * DM;
  float s = 0.f;
#pragma unroll
  for (int i = 0; i < DM / 64; ++i) { float v = xr[lane + i * 64]; s = fmaf(v, v, s); }
#pragma unroll
  for (int off = 32; off >= 1; off >>= 1) s += __shfl_xor(s, off, 64);
  if (lane == 0) rinv[row] = rsqrtf(s * (1.f / DM) + 1e-6f);
}

// ---------------- K1b: xn_bf16 = bf16(x * rinv * norm_w) -------------------
__global__ __launch_bounds__(256) void cvt_xn_k(const float* __restrict__ x,
                                                const float* __restrict__ rinv,
                                                const float* __restrict__ nw,
                                                short* __restrict__ xn) {
  int idx = blockIdx.x * 256 + threadIdx.x;
  int row = idx / (DM / 4);
  int c4 = (idx % (DM / 4)) * 4;
  float rs = rinv[row];
  float4 v = *reinterpret_cast<const float4*>(&x[(size_t)row * DM + c4]);
  float4 w = *reinterpret_cast<const float4*>(&nw[c4]);
  short4v o;
  o.x = (short)f2bf(v.x * rs * w.x); o.y = (short)f2bf(v.y * rs * w.y);
  o.z = (short)f2bf(v.z * rs * w.z); o.w = (short)f2bf(v.w * rs * w.w);
  *reinterpret_cast<short4v*>(&xn[(size_t)row * DM + c4]) = o;
}

// ---------------- K1c: dst[c][r] = bf16(src[r][c]) (tiled transpose) -------
__global__ __launch_bounds__(256) void cvt_transpose_k(const float* __restrict__ src,
                                                       int rows, int cols,
                                                       short* __restrict__ dst) {
  __shared__ float t[32][33];
  int r0 = blockIdx.y * 32, c0 = blockIdx.x * 32;
  int tid = threadIdx.x;
  int lr = tid >> 3, lc4 = (tid & 7) * 4;
  float4 v = *reinterpret_cast<const float4*>(&src[(size_t)(r0 + lr) * cols + c0 + lc4]);
  t[lr][lc4 + 0] = v.x; t[lr][lc4 + 1] = v.y; t[lr][lc4 + 2] = v.z; t[lr][lc4 + 3] = v.w;
  __syncthreads();
  int orow = tid >> 3, oc4 = (tid & 7) * 4;
  short4v o;
  o.x = (short)f2bf(t[oc4 + 0][orow]); o.y = (short)f2bf(t[oc4 + 1][orow]);
  o.z = (short)f2bf(t[oc4 + 2][orow]); o.w = (short)f2bf(t[oc4 + 3][orow]);
  *reinterpret_cast<short4v*>(&dst[(size_t)(c0 + orow) * rows + r0 + oc4]) = o;
}

// ---------------- bf16 MFMA GEMM: C = [res +] A @ B^T ----------------------
__global__ __launch_bounds__(256) void gemm_bf16(
    const short* __restrict__ A, int lda,
    const short* __restrict__ Bt, int ldb,
    float* __restrict__ C, int ldc, int K,
    const float* __restrict__ res, int ldr)
{
  __shared__ __align__(16) short As[128 * 64];
  __shared__ __align__(16) short Bs[128 * 64];
  const int tid = threadIdx.x;
  const int w = tid >> 6, lane = tid & 63;
  const int wr = w >> 1, wc = w & 1;
  const int m0 = blockIdx.y * 128, n0 = blockIdx.x * 128;
  const int l15 = lane & 15, l4 = lane >> 4;

  f32x4 acc[4][4];
#pragma unroll
  for (int i = 0; i < 4; ++i)
#pragma unroll
    for (int j = 0; j < 4; ++j) acc[i][j] = (f32x4){0.f, 0.f, 0.f, 0.f};

  const int srow = (lane >> 3);
  const int skb = (lane & 7) * 8;

  for (int k0 = 0; k0 < K; k0 += 64) {
    __syncthreads();
#pragma unroll
    for (int q = 0; q < 4; ++q) {
      int c = w * 4 + q;
      int row = 8 * c + srow;
      __builtin_amdgcn_global_load_lds(
          (const AS1 unsigned int*)(A + (size_t)(m0 + row) * lda + k0 + skb),
          (AS3 unsigned int*)((char*)As + c * 1024), 16, 0, 0);
      __builtin_amdgcn_global_load_lds(
          (const AS1 unsigned int*)(Bt + (size_t)(n0 + row) * ldb + k0 + skb),
          (AS3 unsigned int*)((char*)Bs + c * 1024), 16, 0, 0);
    }
    __syncthreads();
#pragma unroll
    for (int kk = 0; kk < 2; ++kk) {
      short8 a[4], b[4];
#pragma unroll
      for (int i = 0; i < 4; ++i)
        a[i] = *reinterpret_cast<const short8*>(
            &As[(wr * 64 + i * 16 + l15) * 64 + kk * 32 + l4 * 8]);
#pragma unroll
      for (int j = 0; j < 4; ++j)
        b[j] = *reinterpret_cast<const short8*>(
            &Bs[(wc * 64 + j * 16 + l15) * 64 + kk * 32 + l4 * 8]);
#pragma unroll
      for (int i = 0; i < 4; ++i)
#pragma unroll
        for (int j = 0; j < 4; ++j)
          acc[i][j] = __builtin_amdgcn_mfma_f32_16x16x32_bf16(a[i], b[j], acc[i][j], 0, 0, 0);
    }
  }

#pragma unroll
  for (int i = 0; i < 4; ++i) {
#pragma unroll
    for (int j = 0; j < 4; ++j) {
      int col = n0 + wc * 64 + j * 16 + l15;
#pragma unroll
      for (int r = 0; r < 4; ++r) {
        int row = m0 + wr * 64 + i * 16 + l4 * 4 + r;
        float v = acc[i][j][r];
        if (res) v += res[(size_t)row * ldr + col];
        C[(size_t)row * ldc + col] = v;
      }
    }
  }
}

// ---------------- K3: depthwise causal conv(K=4) + bias + SiLU -------------
__global__ __launch_bounds__(256) void conv_silu_k(const float* __restrict__ xz,
                                                   const float* __restrict__ cw,
                                                   const float* __restrict__ cb,
                                                   float* __restrict__ xc) {
  int idx = blockIdx.x * 256 + threadIdx.x;
  int d = idx % DI;
  int bt = idx / DI;
  int t = bt & (SEQN - 1);
  float acc = cb[d];
  const float4 w4 = *reinterpret_cast<const float4*>(&cw[d * 4]);
  const float wv[4] = {w4.x, w4.y, w4.z, w4.w};
  const float* base = xz + (size_t)bt * 3072 + d;
#pragma unroll
  for (int k = 0; k < 4; ++k) {
    int tt = t + k - 3;
    if (tt >= 0) acc = fmaf(base[(ptrdiff_t)(k - 3) * 3072], wv[k], acc);
  }
  xc[idx] = acc / (1.f + __expf(-acc));
}

// ---------------- K4: x_ssm = xc @ w_x -> Bm(.,16) Cm(.,16) dtr(.) ---------
__global__ __launch_bounds__(256) void xssm_k(const float* __restrict__ xc,
                                              const float* __restrict__ wx,
                                              float* __restrict__ Bm,
                                              float* __restrict__ Cm,
                                              float* __restrict__ dtr) {
  int wv = threadIdx.x >> 6, lane = threadIdx.x & 63;
  int row = blockIdx.x * 4 + wv;
  const float* xr = xc + (size_t)row * DI;
  float acc[33];
#pragma unroll
  for (int j = 0; j < 33; ++j) acc[j] = 0.f;
  for (int k = lane; k < DI; k += 64) {
    float xv = xr[k];
    const float* wr = wx + (size_t)k * 33;
#pragma unroll
    for (int j = 0; j < 33; ++j) acc[j] = fmaf(xv, wr[j], acc[j]);
  }
#pragma unroll
  for (int j = 0; j < 33; ++j) {
#pragma unroll
    for (int off = 32; off >= 1; off >>= 1) acc[j] += __shfl_xor(acc[j], off, 64);
  }
  if (lane == 0) {
#pragma unroll
    for (int j = 0; j < 16; ++j) Bm[(size_t)row * 16 + j] = acc[j];
#pragma unroll
    for (int j = 0; j < 16; ++j) Cm[(size_t)row * 16 + j] = acc[16 + j];
    dtr[row] = acc[32];
  }
}

// ---------------- K5a: per-chunk local scan, thread = one d-channel --------
// grid: blk = ((b*(DI/256) + db)*NCHUNK + c);  768 blocks x 256 thr.
__global__ __launch_bounds__(256) void scan_part1(
    const float* __restrict__ xc,
    const float* __restrict__ Bm, const float* __restrict__ dtr,
    const float* __restrict__ w_dt, const float* __restrict__ b_dt,
    const float* __restrict__ A_log,
    float* __restrict__ hL,     // [B][NCHUNK][DI][16]
    float* __restrict__ Tsum)   // [B][NCHUNK][DI]
{
  const int blk = blockIdx.x;
  const int c  = blk % NCHUNK;
  const int db = (blk / NCHUNK) % (DI / 256);
  const int b  = blk / (NCHUNK * (DI / 256));
  const int tid = threadIdx.x;
  const int d = db * 256 + tid;
  const size_t cb = (size_t)b * SEQN + c * CHUNK;

  __shared__ float sB[CHUNK][16];   // 2KB
  __shared__ float sdt[CHUNK];
  if (tid < CHUNK * 4)
    reinterpret_cast<float4*>(&sB[0][0])[tid] =
        reinterpret_cast<const float4*>(&Bm[cb * 16])[tid];
  if (tid < CHUNK / 4)
    reinterpret_cast<float4*>(sdt)[tid] =
        reinterpret_cast<const float4*>(&dtr[cb])[tid];
  __syncthreads();

  const float wdt = w_dt[d], bdt = b_dt[d];
  float a[DS2], h[DS2];
#pragma unroll
  for (int q = 0; q < 4; ++q) {
    float4 al = *reinterpret_cast<const float4*>(&A_log[(size_t)d * DS2 + q * 4]);
    a[q * 4 + 0] = -__expf(al.x); a[q * 4 + 1] = -__expf(al.y);
    a[q * 4 + 2] = -__expf(al.z); a[q * 4 + 3] = -__expf(al.w);
  }
#pragma unroll
  for (int n = 0; n < DS2; ++n) h[n] = 0.f;
  float T = 0.f;

#pragma unroll 2
  for (int tt = 0; tt < CHUNK; ++tt) {
    float v = fmaf(sdt[tt], wdt, bdt);
    float dtv = (v > 15.f) ? v : __logf(1.f + __expf(v));
    T += dtv;
    float xv = xc[(cb + tt) * DI + d];
    float s = dtv * xv;
    float bb[DS2];
#pragma unroll
    for (int q = 0; q < 4; ++q)
      *reinterpret_cast<float4*>(&bb[q * 4]) =
          *reinterpret_cast<const float4*>(&sB[tt][q * 4]);
#pragma unroll
    for (int n = 0; n < DS2; ++n)
      h[n] = fmaf(__expf(a[n] * dtv), h[n], s * bb[n]);
  }

  const size_t base = (size_t)(b * NCHUNK + c) * DI + d;
#pragma unroll
  for (int q = 0; q < 4; ++q)
    *reinterpret_cast<float4*>(&hL[base * 16 + q * 4]) =
        *reinterpret_cast<const float4*>(&h[q * 4]);
  Tsum[base] = T;
}

// ---------------- K5b: sequential chunk-combine, in place ------------------
// thread = (b,d,n); hL[b][c][d][n] is rewritten to H_init (state BEFORE chunk c)
__global__ __launch_bounds__(256) void scan_combine_k(
    float* __restrict__ hLH, const float* __restrict__ Tsum,
    const float* __restrict__ A_log)
{
  int g = blockIdx.x * 256 + threadIdx.x;   // 0 .. B*DI*16-1
  int n = g & 15;
  int d = (g >> 4) % DI;
  int b = g / (DI * DS2);
  const float a = -__expf(A_log[(size_t)d * DS2 + n]);
  float h = 0.f;
  for (int c = 0; c < NCHUNK; ++c) {
    size_t base = (size_t)(b * NCHUNK + c) * DI + d;
    float hl = hLH[base * 16 + n];
    float T = Tsum[base];
    float hprev = h;
    h = fmaf(__expf(a * T), h, hl);
    hLH[base * 16 + n] = hprev;          // overwrite with H_init
  }
}

// ---------------- K5c: replay chunk with H_init + fused epilogue -----------
__global__ __launch_bounds__(256) void scan_part3(
    const float* __restrict__ xc,
    const float* __restrict__ xz,    // read z at cols 1536..
    short* __restrict__ ybf,
    const float* __restrict__ Bm, const float* __restrict__ Cm,
    const float* __restrict__ dtr,
    const float* __restrict__ w_dt, const float* __restrict__ b_dt,
    const float* __restrict__ A_log, const float* __restrict__ Dp,
    const float* __restrict__ Hinit)
{
  const int blk = blockIdx.x;
  const int c  = blk % NCHUNK;
  const int db = (blk / NCHUNK) % (DI / 256);
  const int b  = blk / (NCHUNK * (DI / 256));
  const int tid = threadIdx.x;
  const int d = db * 256 + tid;
  const size_t cb = (size_t)b * SEQN + c * CHUNK;

  __shared__ float sB[CHUNK][16], sC[CHUNK][16];
  __shared__ float sdt[CHUNK];
  if (tid < CHUNK * 4)
    reinterpret_cast<float4*>(&sB[0][0])[tid] =
        reinterpret_cast<const float4*>(&Bm[cb * 16])[tid];
  else if (tid < CHUNK * 8)
    reinterpret_cast<float4*>(&sC[0][0])[tid - CHUNK * 4] =
        reinterpret_cast<const float4*>(&Cm[cb * 16])[tid - CHUNK * 4];
  if (tid < CHUNK / 4)
    reinterpret_cast<float4*>(sdt)[tid] =
        reinterpret_cast<const float4*>(&dtr[cb])[tid];

  const float wdt = w_dt[d], bdt = b_dt[d];
  const float Dd = Dp[d];
  float a[DS2], h[DS2];
#pragma unroll
  for (int q = 0; q < 4; ++q) {
    float4 al = *reinterpret_cast<const float4*>(&A_log[(size_t)d * DS2 + q * 4]);
    a[q * 4 + 0] = -__expf(al.x); a[q * 4 + 1] = -__expf(al.y);
    a[q * 4 + 2] = -__expf(al.z); a[q * 4 + 3] = -__expf(al.w);
  }
  const size_t base = (size_t)(b * NCHUNK + c) * DI + d;
#pragma unroll
  for (int q = 0; q < 4; ++q)
    *reinterpret_cast<float4*>(&h[q * 4]) =
        *reinterpret_cast<const float4*>(&Hinit[base * 16 + q * 4]);
  __syncthreads();

#pragma unroll 2
  for (int tt = 0; tt < CHUNK; ++tt) {
    float v = fmaf(sdt[tt], wdt, bdt);
    float dtv = (v > 15.f) ? v : __logf(1.f + __expf(v));
    float xv = xc[(cb + tt) * DI + d];
    float s = dtv * xv;
    float bb[DS2], cc[DS2];
#pragma unroll
    for (int q = 0; q < 4; ++q) {
      *reinterpret_cast<float4*>(&bb[q * 4]) =
          *reinterpret_cast<const float4*>(&sB[tt][q * 4]);
      *reinterpret_cast<float4*>(&cc[q * 4]) =
          *reinterpret_cast<const float4*>(&sC[tt][q * 4]);
    }
    float y = 0.f;
#pragma unroll
    for (int n = 0; n < DS2; ++n) {
      h[n] = fmaf(__expf(a[n] * dtv), h[n], s * bb[n]);
      y = fmaf(h[n], cc[n], y);
    }
    const size_t rr = cb + tt;
    float z = xz[rr * 3072 + DI + d];
    float yo = fmaf(xv, Dd, y);
    ybf[rr * DI + d] = (short)f2bf(yo * (z / (1.f + __expf(-z))));
  }
}

// ---------------- launcher -------------------------------------------------
extern "C" void kernel_launch(void* const* d_in, const int* in_sizes, int n_in,
                              void* d_out, int out_size, void* d_ws, size_t ws_size,
                              hipStream_t stream) {
  const float* x      = (const float*)d_in[0];
  const float* norm_w = (const float*)d_in[1];
  const float* w_in   = (const float*)d_in[2];
  const float* conv_w = (const float*)d_in[3];
  const float* conv_b = (const float*)d_in[4];
  const float* w_x    = (const float*)d_in[5];
  const float* w_dt   = (const float*)d_in[6];
  const float* b_dt   = (const float*)d_in[7];
  const float* A_log  = (const float*)d_in[8];
  const float* Dp     = (const float*)d_in[9];
  const float* w_out  = (const float*)d_in[10];
  float* out = (float*)d_out;

  // workspace layout (float units)
  float* ws   = (float*)d_ws;
  float* xz   = ws;                          // 4096 x 3072 f32
  float* xc   = xz + (size_t)NROWS * 2 * DI; // 4096 x 1536 f32
  float* Bm   = xc + (size_t)NROWS * DI;     // 4096 x 16
  float* Cm   = Bm + (size_t)NROWS * 16;
  float* dtr  = Cm + (size_t)NROWS * 16;     // 4096
  float* rinv = dtr + NROWS;                 // 4096
  float* hL   = rinv + NROWS;                // B*NCHUNK*DI*16 = 3.1M
  float* Tsum = hL + (size_t)BSZ * NCHUNK * DI * 16;  // 196K
  short* xnb  = (short*)(Tsum + (size_t)BSZ * NCHUNK * DI);
  short* winT = xnb + (size_t)NROWS * DM;
  short* woutT= winT + (size_t)2 * DI * DM;
  short* ybf  = woutT + (size_t)DM * DI;
  // total ~120 MB

  rms_k<<<NROWS / 4, 256, 0, stream>>>(x, rinv);
  cvt_xn_k<<<(NROWS * DM / 4) / 256, 256, 0, stream>>>(x, rinv, norm_w, xnb);
  cvt_transpose_k<<<dim3(2 * DI / 32, DM / 32), 256, 0, stream>>>(w_in, DM, 2 * DI, winT);
  cvt_transpose_k<<<dim3(DM / 32, DI / 32), 256, 0, stream>>>(w_out, DI, DM, woutT);

  // GEMM1: xz = xn @ w_in   (M=4096 N=3072 K=768)
  gemm_bf16<<<dim3(2 * DI / 128, NROWS / 128), 256, 0, stream>>>(
      xnb, DM, winT, DM, xz, 2 * DI, DM, nullptr, 0);

  conv_silu_k<<<(NROWS * DI) / 256, 256, 0, stream>>>(xz, conv_w, conv_b, xc);
  xssm_k<<<NROWS / 4, 256, 0, stream>>>(xc, w_x, Bm, Cm, dtr);

  const int nblk = BSZ * (DI / 256) * NCHUNK;  // 768
  scan_part1<<<nblk, 256, 0, stream>>>(xc, Bm, dtr, w_dt, b_dt, A_log, hL, Tsum);
  scan_combine_k<<<(BSZ * DI * DS2) / 256, 256, 0, stream>>>(hL, Tsum, A_log);
  scan_part3<<<nblk, 256, 0, stream>>>(xc, xz, ybf, Bm, Cm, dtr, w_dt, b_dt,
                                       A_log, Dp, hL);

  // GEMM3: out = x + y @ w_out   (M=4096 N=768 K=1536)
  gemm_bf16<<<dim3(DM / 128, NROWS / 128), 256, 0, stream>>>(
      ybf, DI, woutT, DI, out, DM, DI, x, DM);
}

// Round 5
// 234.299 us; speedup vs baseline: 7.7249x; 1.2889x over previous
//
#include <hip/hip_runtime.h>
#include <math.h>

// S6 (Mamba-style) block, B=2 S=2048 Dm=768 Di=1536 Ds=16 K=4.
// Round 5: xssm fixed — w_x transposed to [33][DI] (coalesced weight loads,
//          L2-resident) + 2 rows per wave (halves L2 traffic). R4 profile
//          showed xssm 103us at VALUBusy 4% = pure scattered-load stall.
//          Everything else unchanged from Round 4.

#define DM   768
#define DI   1536
#define DS2  16
#define SEQN 2048
#define BSZ  2
#define NROWS (BSZ*SEQN)   // 4096
#define CHUNK 32
#define NCHUNK (SEQN/CHUNK) // 64

#define AS1 __attribute__((address_space(1)))
#define AS3 __attribute__((address_space(3)))

typedef short short8 __attribute__((ext_vector_type(8)));
typedef short short4v __attribute__((ext_vector_type(4)));
typedef float f32x4 __attribute__((ext_vector_type(4)));

__device__ __forceinline__ unsigned short f2bf(float f) {
  unsigned u = __builtin_bit_cast(unsigned, f);
  unsigned r = (u + 0x7FFFu + ((u >> 16) & 1u)) >> 16;   // RTNE
  return (unsigned short)r;
}

// ---------------- K1: per-row inverse RMS of x ----------------
__global__ __launch_bounds__(256) void rms_k(const float* __restrict__ x,
                                             float* __restrict__ rinv) {
  int wv = threadIdx.x >> 6, lane = threadIdx.x & 63;
  int row = blockIdx.x * 4 + wv;
  const float* xr = x + (size_t)row * DM;
  float s = 0.f;
#pragma unroll
  for (int i = 0; i < DM / 64; ++i) { float v = xr[lane + i * 64]; s = fmaf(v, v, s); }
#pragma unroll
  for (int off = 32; off >= 1; off >>= 1) s += __shfl_xor(s, off, 64);
  if (lane == 0) rinv[row] = rsqrtf(s * (1.f / DM) + 1e-6f);
}

// ---------------- K1b: xn_bf16 = bf16(x * rinv * norm_w) -------------------
__global__ __launch_bounds__(256) void cvt_xn_k(const float* __restrict__ x,
                                                const float* __restrict__ rinv,
                                                const float* __restrict__ nw,
                                                short* __restrict__ xn) {
  int idx = blockIdx.x * 256 + threadIdx.x;
  int row = idx / (DM / 4);
  int c4 = (idx % (DM / 4)) * 4;
  float rs = rinv[row];
  float4 v = *reinterpret_cast<const float4*>(&x[(size_t)row * DM + c4]);
  float4 w = *reinterpret_cast<const float4*>(&nw[c4]);
  short4v o;
  o.x = (short)f2bf(v.x * rs * w.x); o.y = (short)f2bf(v.y * rs * w.y);
  o.z = (short)f2bf(v.z * rs * w.z); o.w = (short)f2bf(v.w * rs * w.w);
  *reinterpret_cast<short4v*>(&xn[(size_t)row * DM + c4]) = o;
}

// ---------------- K1c: dst[c][r] = bf16(src[r][c]) (tiled transpose) -------
__global__ __launch_bounds__(256) void cvt_transpose_k(const float* __restrict__ src,
                                                       int rows, int cols,
                                                       short* __restrict__ dst) {
  __shared__ float t[32][33];
  int r0 = blockIdx.y * 32, c0 = blockIdx.x * 32;
  int tid = threadIdx.x;
  int lr = tid >> 3, lc4 = (tid & 7) * 4;
  float4 v = *reinterpret_cast<const float4*>(&src[(size_t)(r0 + lr) * cols + c0 + lc4]);
  t[lr][lc4 + 0] = v.x; t[lr][lc4 + 1] = v.y; t[lr][lc4 + 2] = v.z; t[lr][lc4 + 3] = v.w;
  __syncthreads();
  int orow = tid >> 3, oc4 = (tid & 7) * 4;
  short4v o;
  o.x = (short)f2bf(t[oc4 + 0][orow]); o.y = (short)f2bf(t[oc4 + 1][orow]);
  o.z = (short)f2bf(t[oc4 + 2][orow]); o.w = (short)f2bf(t[oc4 + 3][orow]);
  *reinterpret_cast<short4v*>(&dst[(size_t)(c0 + orow) * rows + r0 + oc4]) = o;
}

// ---------------- K1d: wxT[j][k] = wx[k][j]  (33 x 1536, f32) --------------
__global__ __launch_bounds__(256) void wxT_k(const float* __restrict__ wx,
                                             float* __restrict__ wxT) {
  int idx = blockIdx.x * 256 + threadIdx.x;   // over DI*33
  if (idx >= DI * 33) return;
  int k = idx / 33, j = idx % 33;
  wxT[(size_t)j * DI + k] = wx[idx];
}

// ---------------- bf16 MFMA GEMM: C = [res +] A @ B^T ----------------------
__global__ __launch_bounds__(256) void gemm_bf16(
    const short* __restrict__ A, int lda,
    const short* __restrict__ Bt, int ldb,
    float* __restrict__ C, int ldc, int K,
    const float* __restrict__ res, int ldr)
{
  __shared__ __align__(16) short As[128 * 64];
  __shared__ __align__(16) short Bs[128 * 64];
  const int tid = threadIdx.x;
  const int w = tid >> 6, lane = tid & 63;
  const int wr = w >> 1, wc = w & 1;
  const int m0 = blockIdx.y * 128, n0 = blockIdx.x * 128;
  const int l15 = lane & 15, l4 = lane >> 4;

  f32x4 acc[4][4];
#pragma unroll
  for (int i = 0; i < 4; ++i)
#pragma unroll
    for (int j = 0; j < 4; ++j) acc[i][j] = (f32x4){0.f, 0.f, 0.f, 0.f};

  const int srow = (lane >> 3);
  const int skb = (lane & 7) * 8;

  for (int k0 = 0; k0 < K; k0 += 64) {
    __syncthreads();
#pragma unroll
    for (int q = 0; q < 4; ++q) {
      int c = w * 4 + q;
      int row = 8 * c + srow;
      __builtin_amdgcn_global_load_lds(
          (const AS1 unsigned int*)(A + (size_t)(m0 + row) * lda + k0 + skb),
          (AS3 unsigned int*)((char*)As + c * 1024), 16, 0, 0);
      __builtin_amdgcn_global_load_lds(
          (const AS1 unsigned int*)(Bt + (size_t)(n0 + row) * ldb + k0 + skb),
          (AS3 unsigned int*)((char*)Bs + c * 1024), 16, 0, 0);
    }
    __syncthreads();
#pragma unroll
    for (int kk = 0; kk < 2; ++kk) {
      short8 a[4], b[4];
#pragma unroll
      for (int i = 0; i < 4; ++i)
        a[i] = *reinterpret_cast<const short8*>(
            &As[(wr * 64 + i * 16 + l15) * 64 + kk * 32 + l4 * 8]);
#pragma unroll
      for (int j = 0; j < 4; ++j)
        b[j] = *reinterpret_cast<const short8*>(
            &Bs[(wc * 64 + j * 16 + l15) * 64 + kk * 32 + l4 * 8]);
#pragma unroll
      for (int i = 0; i < 4; ++i)
#pragma unroll
        for (int j = 0; j < 4; ++j)
          acc[i][j] = __builtin_amdgcn_mfma_f32_16x16x32_bf16(a[i], b[j], acc[i][j], 0, 0, 0);
    }
  }

#pragma unroll
  for (int i = 0; i < 4; ++i) {
#pragma unroll
    for (int j = 0; j < 4; ++j) {
      int col = n0 + wc * 64 + j * 16 + l15;
#pragma unroll
      for (int r = 0; r < 4; ++r) {
        int row = m0 + wr * 64 + i * 16 + l4 * 4 + r;
        float v = acc[i][j][r];
        if (res) v += res[(size_t)row * ldr + col];
        C[(size_t)row * ldc + col] = v;
      }
    }
  }
}

// ---------------- K3: depthwise causal conv(K=4) + bias + SiLU -------------
__global__ __launch_bounds__(256) void conv_silu_k(const float* __restrict__ xz,
                                                   const float* __restrict__ cw,
                                                   const float* __restrict__ cb,
                                                   float* __restrict__ xc) {
  int idx = blockIdx.x * 256 + threadIdx.x;
  int d = idx % DI;
  int bt = idx / DI;
  int t = bt & (SEQN - 1);
  float acc = cb[d];
  const float4 w4 = *reinterpret_cast<const float4*>(&cw[d * 4]);
  const float wv[4] = {w4.x, w4.y, w4.z, w4.w};
  const float* base = xz + (size_t)bt * 3072 + d;
#pragma unroll
  for (int k = 0; k < 4; ++k) {
    int tt = t + k - 3;
    if (tt >= 0) acc = fmaf(base[(ptrdiff_t)(k - 3) * 3072], wv[k], acc);
  }
  xc[idx] = acc / (1.f + __expf(-acc));
}

// ---------------- K4: x_ssm = xc @ wxT^T, 2 rows per wave ------------------
// wxT: [33][DI] f32. Coalesced loads; wxT is L2-resident (202 KB).
__global__ __launch_bounds__(256) void xssm_k(const float* __restrict__ xc,
                                              const float* __restrict__ wxT,
                                              float* __restrict__ Bm,
                                              float* __restrict__ Cm,
                                              float* __restrict__ dtr) {
  int wv = threadIdx.x >> 6, lane = threadIdx.x & 63;
  int row0 = (blockIdx.x * 4 + wv) * 2;      // grid=512 -> 4096 rows
  const float* xr0 = xc + (size_t)row0 * DI;
  const float* xr1 = xr0 + DI;
  float a0[33], a1[33];
#pragma unroll
  for (int j = 0; j < 33; ++j) { a0[j] = 0.f; a1[j] = 0.f; }
  for (int k = lane; k < DI; k += 64) {
    float x0 = xr0[k], x1 = xr1[k];
#pragma unroll
    for (int j = 0; j < 33; ++j) {
      float w = wxT[(size_t)j * DI + k];
      a0[j] = fmaf(x0, w, a0[j]);
      a1[j] = fmaf(x1, w, a1[j]);
    }
  }
#pragma unroll
  for (int j = 0; j < 33; ++j) {
#pragma unroll
    for (int off = 32; off >= 1; off >>= 1) {
      a0[j] += __shfl_xor(a0[j], off, 64);
      a1[j] += __shfl_xor(a1[j], off, 64);
    }
  }
  if (lane == 0) {
#pragma unroll
    for (int j = 0; j < 16; ++j) Bm[(size_t)row0 * 16 + j] = a0[j];
#pragma unroll
    for (int j = 0; j < 16; ++j) Cm[(size_t)row0 * 16 + j] = a0[16 + j];
    dtr[row0] = a0[32];
#pragma unroll
    for (int j = 0; j < 16; ++j) Bm[(size_t)(row0 + 1) * 16 + j] = a1[j];
#pragma unroll
    for (int j = 0; j < 16; ++j) Cm[(size_t)(row0 + 1) * 16 + j] = a1[16 + j];
    dtr[row0 + 1] = a1[32];
  }
}

// ---------------- K5a: per-chunk local scan, thread = one d-channel --------
__global__ __launch_bounds__(256) void scan_part1(
    const float* __restrict__ xc,
    const float* __restrict__ Bm, const float* __restrict__ dtr,
    const float* __restrict__ w_dt, const float* __restrict__ b_dt,
    const float* __restrict__ A_log,
    float* __restrict__ hL, float* __restrict__ Tsum)
{
  const int blk = blockIdx.x;
  const int c  = blk % NCHUNK;
  const int db = (blk / NCHUNK) % (DI / 256);
  const int b  = blk / (NCHUNK * (DI / 256));
  const int tid = threadIdx.x;
  const int d = db * 256 + tid;
  const size_t cb = (size_t)b * SEQN + c * CHUNK;

  __shared__ float sB[CHUNK][16];
  __shared__ float sdt[CHUNK];
  if (tid < CHUNK * 4)
    reinterpret_cast<float4*>(&sB[0][0])[tid] =
        reinterpret_cast<const float4*>(&Bm[cb * 16])[tid];
  if (tid < CHUNK / 4)
    reinterpret_cast<float4*>(sdt)[tid] =
        reinterpret_cast<const float4*>(&dtr[cb])[tid];
  __syncthreads();

  const float wdt = w_dt[d], bdt = b_dt[d];
  float a[DS2], h[DS2];
#pragma unroll
  for (int q = 0; q < 4; ++q) {
    float4 al = *reinterpret_cast<const float4*>(&A_log[(size_t)d * DS2 + q * 4]);
    a[q * 4 + 0] = -__expf(al.x); a[q * 4 + 1] = -__expf(al.y);
    a[q * 4 + 2] = -__expf(al.z); a[q * 4 + 3] = -__expf(al.w);
  }
#pragma unroll
  for (int n = 0; n < DS2; ++n) h[n] = 0.f;
  float T = 0.f;

#pragma unroll 2
  for (int tt = 0; tt < CHUNK; ++tt) {
    float v = fmaf(sdt[tt], wdt, bdt);
    float dtv = (v > 15.f) ? v : __logf(1.f + __expf(v));
    T += dtv;
    float xv = xc[(cb + tt) * DI + d];
    float s = dtv * xv;
    float bb[DS2];
#pragma unroll
    for (int q = 0; q < 4; ++q)
      *reinterpret_cast<float4*>(&bb[q * 4]) =
          *reinterpret_cast<const float4*>(&sB[tt][q * 4]);
#pragma unroll
    for (int n = 0; n < DS2; ++n)
      h[n] = fmaf(__expf(a[n] * dtv), h[n], s * bb[n]);
  }

  const size_t base = (size_t)(b * NCHUNK + c) * DI + d;
#pragma unroll
  for (int q = 0; q < 4; ++q)
    *reinterpret_cast<float4*>(&hL[base * 16 + q * 4]) =
        *reinterpret_cast<const float4*>(&h[q * 4]);
  Tsum[base] = T;
}

// ---------------- K5b: sequential chunk-combine, in place ------------------
__global__ __launch_bounds__(256) void scan_combine_k(
    float* __restrict__ hLH, const float* __restrict__ Tsum,
    const float* __restrict__ A_log)
{
  int g = blockIdx.x * 256 + threadIdx.x;
  int n = g & 15;
  int d = (g >> 4) % DI;
  int b = g / (DI * DS2);
  const float a = -__expf(A_log[(size_t)d * DS2 + n]);
  float h = 0.f;
  for (int c = 0; c < NCHUNK; ++c) {
    size_t base = (size_t)(b * NCHUNK + c) * DI + d;
    float hl = hLH[base * 16 + n];
    float T = Tsum[base];
    float hprev = h;
    h = fmaf(__expf(a * T), h, hl);
    hLH[base * 16 + n] = hprev;
  }
}

// ---------------- K5c: replay chunk with H_init + fused epilogue -----------
__global__ __launch_bounds__(256) void scan_part3(
    const float* __restrict__ xc,
    const float* __restrict__ xz,
    short* __restrict__ ybf,
    const float* __restrict__ Bm, const float* __restrict__ Cm,
    const float* __restrict__ dtr,
    const float* __restrict__ w_dt, const float* __restrict__ b_dt,
    const float* __restrict__ A_log, const float* __restrict__ Dp,
    const float* __restrict__ Hinit)
{
  const int blk = blockIdx.x;
  const int c  = blk % NCHUNK;
  const int db = (blk / NCHUNK) % (DI / 256);
  const int b  = blk / (NCHUNK * (DI / 256));
  const int tid = threadIdx.x;
  const int d = db * 256 + tid;
  const size_t cb = (size_t)b * SEQN + c * CHUNK;

  __shared__ float sB[CHUNK][16], sC[CHUNK][16];
  __shared__ float sdt[CHUNK];
  if (tid < CHUNK * 4)
    reinterpret_cast<float4*>(&sB[0][0])[tid] =
        reinterpret_cast<const float4*>(&Bm[cb * 16])[tid];
  else if (tid < CHUNK * 8)
    reinterpret_cast<float4*>(&sC[0][0])[tid - CHUNK * 4] =
        reinterpret_cast<const float4*>(&Cm[cb * 16])[tid - CHUNK * 4];
  if (tid < CHUNK / 4)
    reinterpret_cast<float4*>(sdt)[tid] =
        reinterpret_cast<const float4*>(&dtr[cb])[tid];

  const float wdt = w_dt[d], bdt = b_dt[d];
  const float Dd = Dp[d];
  float a[DS2], h[DS2];
#pragma unroll
  for (int q = 0; q < 4; ++q) {
    float4 al = *reinterpret_cast<const float4*>(&A_log[(size_t)d * DS2 + q * 4]);
    a[q * 4 + 0] = -__expf(al.x); a[q * 4 + 1] = -__expf(al.y);
    a[q * 4 + 2] = -__expf(al.z); a[q * 4 + 3] = -__expf(al.w);
  }
  const size_t base = (size_t)(b * NCHUNK + c) * DI + d;
#pragma unroll
  for (int q = 0; q < 4; ++q)
    *reinterpret_cast<float4*>(&h[q * 4]) =
        *reinterpret_cast<const float4*>(&Hinit[base * 16 + q * 4]);
  __syncthreads();

#pragma unroll 2
  for (int tt = 0; tt < CHUNK; ++tt) {
    float v = fmaf(sdt[tt], wdt, bdt);
    float dtv = (v > 15.f) ? v : __logf(1.f + __expf(v));
    float xv = xc[(cb + tt) * DI + d];
    float s = dtv * xv;
    float bb[DS2], cc[DS2];
#pragma unroll
    for (int q = 0; q < 4; ++q) {
      *reinterpret_cast<float4*>(&bb[q * 4]) =
          *reinterpret_cast<const float4*>(&sB[tt][q * 4]);
      *reinterpret_cast<float4*>(&cc[q * 4]) =
          *reinterpret_cast<const float4*>(&sC[tt][q * 4]);
    }
    float y = 0.f;
#pragma unroll
    for (int n = 0; n < DS2; ++n) {
      h[n] = fmaf(__expf(a[n] * dtv), h[n], s * bb[n]);
      y = fmaf(h[n], cc[n], y);
    }
    const size_t rr = cb + tt;
    float z = xz[rr * 3072 + DI + d];
    float yo = fmaf(xv, Dd, y);
    ybf[rr * DI + d] = (short)f2bf(yo * (z / (1.f + __expf(-z))));
  }
}

// ---------------- launcher -------------------------------------------------
extern "C" void kernel_launch(void* const* d_in, const int* in_sizes, int n_in,
                              void* d_out, int out_size, void* d_ws, size_t ws_size,
                              hipStream_t stream) {
  const float* x      = (const float*)d_in[0];
  const float* norm_w = (const float*)d_in[1];
  const float* w_in   = (const float*)d_in[2];
  const float* conv_w = (const float*)d_in[3];
  const float* conv_b = (const float*)d_in[4];
  const float* w_x    = (const float*)d_in[5];
  const float* w_dt   = (const float*)d_in[6];
  const float* b_dt   = (const float*)d_in[7];
  const float* A_log  = (const float*)d_in[8];
  const float* Dp     = (const float*)d_in[9];
  const float* w_out  = (const float*)d_in[10];
  float* out = (float*)d_out;

  // workspace layout (float units)
  float* ws   = (float*)d_ws;
  float* xz   = ws;                          // 4096 x 3072 f32
  float* xc   = xz + (size_t)NROWS * 2 * DI; // 4096 x 1536 f32
  float* Bm   = xc + (size_t)NROWS * DI;     // 4096 x 16
  float* Cm   = Bm + (size_t)NROWS * 16;
  float* dtr  = Cm + (size_t)NROWS * 16;     // 4096
  float* rinv = dtr + NROWS;                 // 4096
  float* hL   = rinv + NROWS;                // B*NCHUNK*DI*16 = 3.1M
  float* Tsum = hL + (size_t)BSZ * NCHUNK * DI * 16;  // 196K
  float* wxT  = Tsum + (size_t)BSZ * NCHUNK * DI;     // 33*1536 = 50688
  short* xnb  = (short*)(wxT + (size_t)33 * DI);
  short* winT = xnb + (size_t)NROWS * DM;
  short* woutT= winT + (size_t)2 * DI * DM;
  short* ybf  = woutT + (size_t)DM * DI;
  // total ~120 MB

  rms_k<<<NROWS / 4, 256, 0, stream>>>(x, rinv);
  cvt_xn_k<<<(NROWS * DM / 4) / 256, 256, 0, stream>>>(x, rinv, norm_w, xnb);
  cvt_transpose_k<<<dim3(2 * DI / 32, DM / 32), 256, 0, stream>>>(w_in, DM, 2 * DI, winT);
  cvt_transpose_k<<<dim3(DM / 32, DI / 32), 256, 0, stream>>>(w_out, DI, DM, woutT);
  wxT_k<<<(DI * 33 + 255) / 256, 256, 0, stream>>>(w_x, wxT);

  // GEMM1: xz = xn @ w_in   (M=4096 N=3072 K=768)
  gemm_bf16<<<dim3(2 * DI / 128, NROWS / 128), 256, 0, stream>>>(
      xnb, DM, winT, DM, xz, 2 * DI, DM, nullptr, 0);

  conv_silu_k<<<(NROWS * DI) / 256, 256, 0, stream>>>(xz, conv_w, conv_b, xc);
  xssm_k<<<NROWS / 8, 256, 0, stream>>>(xc, wxT, Bm, Cm, dtr);

  const int nblk = BSZ * (DI / 256) * NCHUNK;  // 768
  scan_part1<<<nblk, 256, 0, stream>>>(xc, Bm, dtr, w_dt, b_dt, A_log, hL, Tsum);
  scan_combine_k<<<(BSZ * DI * DS2) / 256, 256, 0, stream>>>(hL, Tsum, A_log);
  scan_part3<<<nblk, 256, 0, stream>>>(xc, xz, ybf, Bm, Cm, dtr, w_dt, b_dt,
                                       A_log, Dp, hL);

  // GEMM3: out = x + y @ w_out   (M=4096 N=768 K=1536)
  gemm_bf16<<<dim3(DM / 128, NROWS / 128), 256, 0, stream>>>(
      ybf, DI, woutT, DI, out, DM, DI, x, DM);
}

// Round 6
// 211.209 us; speedup vs baseline: 8.5695x; 1.1093x over previous
//
#include <hip/hip_runtime.h>
#include <math.h>

// S6 (Mamba-style) block, B=2 S=2048 Dm=768 Di=1536 Ds=16 K=4.
// Round 6: (a) GEMM templated on tile size; GEMM3 -> 64x64 tile (768 blocks,
//          was 192 — R5 showed it latency-starved at <1 block/CU).
//          (b) GEMM1 writes xz as bf16 (halves 50MB C-write + conv fetch).
//          Scan/xssm/conv logic unchanged (conv/scan now read bf16 xz).

#define DM   768
#define DI   1536
#define DS2  16
#define SEQN 2048
#define BSZ  2
#define NROWS (BSZ*SEQN)   // 4096
#define CHUNK 32
#define NCHUNK (SEQN/CHUNK) // 64

#define AS1 __attribute__((address_space(1)))
#define AS3 __attribute__((address_space(3)))

typedef short short8 __attribute__((ext_vector_type(8)));
typedef short short4v __attribute__((ext_vector_type(4)));
typedef float f32x4 __attribute__((ext_vector_type(4)));

__device__ __forceinline__ unsigned short f2bf(float f) {
  unsigned u = __builtin_bit_cast(unsigned, f);
  unsigned r = (u + 0x7FFFu + ((u >> 16) & 1u)) >> 16;   // RTNE
  return (unsigned short)r;
}
__device__ __forceinline__ float bf2f(short s) {
  unsigned u = ((unsigned)(unsigned short)s) << 16;
  return __builtin_bit_cast(float, u);
}

// ---------------- K1: per-row inverse RMS of x ----------------
__global__ __launch_bounds__(256) void rms_k(const float* __restrict__ x,
                                             float* __restrict__ rinv) {
  int wv = threadIdx.x >> 6, lane = threadIdx.x & 63;
  int row = blockIdx.x * 4 + wv;
  const float* xr = x + (size_t)row * DM;
  float s = 0.f;
#pragma unroll
  for (int i = 0; i < DM / 64; ++i) { float v = xr[lane + i * 64]; s = fmaf(v, v, s); }
#pragma unroll
  for (int off = 32; off >= 1; off >>= 1) s += __shfl_xor(s, off, 64);
  if (lane == 0) rinv[row] = rsqrtf(s * (1.f / DM) + 1e-6f);
}

// ---------------- K1b: xn_bf16 = bf16(x * rinv * norm_w) -------------------
__global__ __launch_bounds__(256) void cvt_xn_k(const float* __restrict__ x,
                                                const float* __restrict__ rinv,
                                                const float* __restrict__ nw,
                                                short* __restrict__ xn) {
  int idx = blockIdx.x * 256 + threadIdx.x;
  int row = idx / (DM / 4);
  int c4 = (idx % (DM / 4)) * 4;
  float rs = rinv[row];
  float4 v = *reinterpret_cast<const float4*>(&x[(size_t)row * DM + c4]);
  float4 w = *reinterpret_cast<const float4*>(&nw[c4]);
  short4v o;
  o.x = (short)f2bf(v.x * rs * w.x); o.y = (short)f2bf(v.y * rs * w.y);
  o.z = (short)f2bf(v.z * rs * w.z); o.w = (short)f2bf(v.w * rs * w.w);
  *reinterpret_cast<short4v*>(&xn[(size_t)row * DM + c4]) = o;
}

// ---------------- K1c: dst[c][r] = bf16(src[r][c]) (tiled transpose) -------
__global__ __launch_bounds__(256) void cvt_transpose_k(const float* __restrict__ src,
                                                       int rows, int cols,
                                                       short* __restrict__ dst) {
  __shared__ float t[32][33];
  int r0 = blockIdx.y * 32, c0 = blockIdx.x * 32;
  int tid = threadIdx.x;
  int lr = tid >> 3, lc4 = (tid & 7) * 4;
  float4 v = *reinterpret_cast<const float4*>(&src[(size_t)(r0 + lr) * cols + c0 + lc4]);
  t[lr][lc4 + 0] = v.x; t[lr][lc4 + 1] = v.y; t[lr][lc4 + 2] = v.z; t[lr][lc4 + 3] = v.w;
  __syncthreads();
  int orow = tid >> 3, oc4 = (tid & 7) * 4;
  short4v o;
  o.x = (short)f2bf(t[oc4 + 0][orow]); o.y = (short)f2bf(t[oc4 + 1][orow]);
  o.z = (short)f2bf(t[oc4 + 2][orow]); o.w = (short)f2bf(t[oc4 + 3][orow]);
  *reinterpret_cast<short4v*>(&dst[(size_t)(c0 + orow) * rows + r0 + oc4]) = o;
}

// ---------------- K1d: wxT[j][k] = wx[k][j]  (33 x 1536, f32) --------------
__global__ __launch_bounds__(256) void wxT_k(const float* __restrict__ wx,
                                             float* __restrict__ wxT) {
  int idx = blockIdx.x * 256 + threadIdx.x;
  if (idx >= DI * 33) return;
  int k = idx / 33, j = idx % 33;
  wxT[(size_t)j * DI + k] = wx[idx];
}

// ---------------- bf16 MFMA GEMM (templated tile): C = [res +] A @ B^T -----
// A: [M][K] bf16, Bt: [N][K] bf16. BMxBN tile, BK=64, 4 waves (2x2),
// each wave (BM/2)x(BN/2) via (BM/32)x(BN/32) 16x16x32 frags.
template<int BM, int BN, bool OUTBF>
__global__ __launch_bounds__(256) void gemm_bf16(
    const short* __restrict__ A, int lda,
    const short* __restrict__ Bt, int ldb,
    void* __restrict__ Cv, int ldc, int K,
    const float* __restrict__ res, int ldr)
{
  constexpr int MI = BM / 32, NJ = BN / 32;
  __shared__ __align__(16) short As[BM * 64];
  __shared__ __align__(16) short Bs[BN * 64];
  const int tid = threadIdx.x;
  const int w = tid >> 6, lane = tid & 63;
  const int wr = w >> 1, wc = w & 1;
  const int m0 = blockIdx.y * BM, n0 = blockIdx.x * BN;
  const int l15 = lane & 15, l4 = lane >> 4;

  f32x4 acc[MI][NJ];
#pragma unroll
  for (int i = 0; i < MI; ++i)
#pragma unroll
    for (int j = 0; j < NJ; ++j) acc[i][j] = (f32x4){0.f, 0.f, 0.f, 0.f};

  const int srow = lane >> 3;          // row within 8-row chunk
  const int skb = (lane & 7) * 8;      // k offset (16B per lane)

  for (int k0 = 0; k0 < K; k0 += 64) {
    __syncthreads();
#pragma unroll
    for (int q = 0; q < MI; ++q) {     // A: BM/8 chunks, BM/32 per wave
      int c = w * MI + q;
      int row = 8 * c + srow;
      __builtin_amdgcn_global_load_lds(
          (const AS1 unsigned int*)(A + (size_t)(m0 + row) * lda + k0 + skb),
          (AS3 unsigned int*)((char*)As + c * 1024), 16, 0, 0);
    }
#pragma unroll
    for (int q = 0; q < NJ; ++q) {
      int c = w * NJ + q;
      int row = 8 * c + srow;
      __builtin_amdgcn_global_load_lds(
          (const AS1 unsigned int*)(Bt + (size_t)(n0 + row) * ldb + k0 + skb),
          (AS3 unsigned int*)((char*)Bs + c * 1024), 16, 0, 0);
    }
    __syncthreads();
#pragma unroll
    for (int kk = 0; kk < 2; ++kk) {
      short8 a[MI], b[NJ];
#pragma unroll
      for (int i = 0; i < MI; ++i)
        a[i] = *reinterpret_cast<const short8*>(
            &As[(wr * (BM / 2) + i * 16 + l15) * 64 + kk * 32 + l4 * 8]);
#pragma unroll
      for (int j = 0; j < NJ; ++j)
        b[j] = *reinterpret_cast<const short8*>(
            &Bs[(wc * (BN / 2) + j * 16 + l15) * 64 + kk * 32 + l4 * 8]);
#pragma unroll
      for (int i = 0; i < MI; ++i)
#pragma unroll
        for (int j = 0; j < NJ; ++j)
          acc[i][j] = __builtin_amdgcn_mfma_f32_16x16x32_bf16(a[i], b[j], acc[i][j], 0, 0, 0);
    }
  }

#pragma unroll
  for (int i = 0; i < MI; ++i) {
#pragma unroll
    for (int j = 0; j < NJ; ++j) {
      int col = n0 + wc * (BN / 2) + j * 16 + l15;
#pragma unroll
      for (int r = 0; r < 4; ++r) {
        int row = m0 + wr * (BM / 2) + i * 16 + l4 * 4 + r;
        float v = acc[i][j][r];
        if constexpr (OUTBF) {
          ((short*)Cv)[(size_t)row * ldc + col] = (short)f2bf(v);
        } else {
          if (res) v += res[(size_t)row * ldr + col];
          ((float*)Cv)[(size_t)row * ldc + col] = v;
        }
      }
    }
  }
}

// ---------------- K3: depthwise causal conv(K=4) + bias + SiLU -------------
// reads bf16 xz[:, 0:1536], writes f32 xc
__global__ __launch_bounds__(256) void conv_silu_k(const short* __restrict__ xz,
                                                   const float* __restrict__ cw,
                                                   const float* __restrict__ cb,
                                                   float* __restrict__ xc) {
  int idx = blockIdx.x * 256 + threadIdx.x;
  int d = idx % DI;
  int bt = idx / DI;
  int t = bt & (SEQN - 1);
  float acc = cb[d];
  const float4 w4 = *reinterpret_cast<const float4*>(&cw[d * 4]);
  const float wv[4] = {w4.x, w4.y, w4.z, w4.w};
  const short* base = xz + (size_t)bt * 3072 + d;
#pragma unroll
  for (int k = 0; k < 4; ++k) {
    int tt = t + k - 3;
    if (tt >= 0) acc = fmaf(bf2f(base[(ptrdiff_t)(k - 3) * 3072]), wv[k], acc);
  }
  xc[idx] = acc / (1.f + __expf(-acc));
}

// ---------------- K4: x_ssm = xc @ wxT^T, 2 rows per wave ------------------
__global__ __launch_bounds__(256) void xssm_k(const float* __restrict__ xc,
                                              const float* __restrict__ wxT,
                                              float* __restrict__ Bm,
                                              float* __restrict__ Cm,
                                              float* __restrict__ dtr) {
  int wv = threadIdx.x >> 6, lane = threadIdx.x & 63;
  int row0 = (blockIdx.x * 4 + wv) * 2;
  const float* xr0 = xc + (size_t)row0 * DI;
  const float* xr1 = xr0 + DI;
  float a0[33], a1[33];
#pragma unroll
  for (int j = 0; j < 33; ++j) { a0[j] = 0.f; a1[j] = 0.f; }
  for (int k = lane; k < DI; k += 64) {
    float x0 = xr0[k], x1 = xr1[k];
#pragma unroll
    for (int j = 0; j < 33; ++j) {
      float w = wxT[(size_t)j * DI + k];
      a0[j] = fmaf(x0, w, a0[j]);
      a1[j] = fmaf(x1, w, a1[j]);
    }
  }
#pragma unroll
  for (int j = 0; j < 33; ++j) {
#pragma unroll
    for (int off = 32; off >= 1; off >>= 1) {
      a0[j] += __shfl_xor(a0[j], off, 64);
      a1[j] += __shfl_xor(a1[j], off, 64);
    }
  }
  if (lane == 0) {
#pragma unroll
    for (int j = 0; j < 16; ++j) Bm[(size_t)row0 * 16 + j] = a0[j];
#pragma unroll
    for (int j = 0; j < 16; ++j) Cm[(size_t)row0 * 16 + j] = a0[16 + j];
    dtr[row0] = a0[32];
#pragma unroll
    for (int j = 0; j < 16; ++j) Bm[(size_t)(row0 + 1) * 16 + j] = a1[j];
#pragma unroll
    for (int j = 0; j < 16; ++j) Cm[(size_t)(row0 + 1) * 16 + j] = a1[16 + j];
    dtr[row0 + 1] = a1[32];
  }
}

// ---------------- K5a: per-chunk local scan, thread = one d-channel --------
__global__ __launch_bounds__(256) void scan_part1(
    const float* __restrict__ xc,
    const float* __restrict__ Bm, const float* __restrict__ dtr,
    const float* __restrict__ w_dt, const float* __restrict__ b_dt,
    const float* __restrict__ A_log,
    float* __restrict__ hL, float* __restrict__ Tsum)
{
  const int blk = blockIdx.x;
  const int c  = blk % NCHUNK;
  const int db = (blk / NCHUNK) % (DI / 256);
  const int b  = blk / (NCHUNK * (DI / 256));
  const int tid = threadIdx.x;
  const int d = db * 256 + tid;
  const size_t cb = (size_t)b * SEQN + c * CHUNK;

  __shared__ float sB[CHUNK][16];
  __shared__ float sdt[CHUNK];
  if (tid < CHUNK * 4)
    reinterpret_cast<float4*>(&sB[0][0])[tid] =
        reinterpret_cast<const float4*>(&Bm[cb * 16])[tid];
  if (tid < CHUNK / 4)
    reinterpret_cast<float4*>(sdt)[tid] =
        reinterpret_cast<const float4*>(&dtr[cb])[tid];
  __syncthreads();

  const float wdt = w_dt[d], bdt = b_dt[d];
  float a[DS2], h[DS2];
#pragma unroll
  for (int q = 0; q < 4; ++q) {
    float4 al = *reinterpret_cast<const float4*>(&A_log[(size_t)d * DS2 + q * 4]);
    a[q * 4 + 0] = -__expf(al.x); a[q * 4 + 1] = -__expf(al.y);
    a[q * 4 + 2] = -__expf(al.z); a[q * 4 + 3] = -__expf(al.w);
  }
#pragma unroll
  for (int n = 0; n < DS2; ++n) h[n] = 0.f;
  float T = 0.f;

#pragma unroll 2
  for (int tt = 0; tt < CHUNK; ++tt) {
    float v = fmaf(sdt[tt], wdt, bdt);
    float dtv = (v > 15.f) ? v : __logf(1.f + __expf(v));
    T += dtv;
    float xv = xc[(cb + tt) * DI + d];
    float s = dtv * xv;
    float bb[DS2];
#pragma unroll
    for (int q = 0; q < 4; ++q)
      *reinterpret_cast<float4*>(&bb[q * 4]) =
          *reinterpret_cast<const float4*>(&sB[tt][q * 4]);
#pragma unroll
    for (int n = 0; n < DS2; ++n)
      h[n] = fmaf(__expf(a[n] * dtv), h[n], s * bb[n]);
  }

  const size_t base = (size_t)(b * NCHUNK + c) * DI + d;
#pragma unroll
  for (int q = 0; q < 4; ++q)
    *reinterpret_cast<float4*>(&hL[base * 16 + q * 4]) =
        *reinterpret_cast<const float4*>(&h[q * 4]);
  Tsum[base] = T;
}

// ---------------- K5b: sequential chunk-combine, in place ------------------
__global__ __launch_bounds__(256) void scan_combine_k(
    float* __restrict__ hLH, const float* __restrict__ Tsum,
    const float* __restrict__ A_log)
{
  int g = blockIdx.x * 256 + threadIdx.x;
  int n = g & 15;
  int d = (g >> 4) % DI;
  int b = g / (DI * DS2);
  const float a = -__expf(A_log[(size_t)d * DS2 + n]);
  float h = 0.f;
  for (int c = 0; c < NCHUNK; ++c) {
    size_t base = (size_t)(b * NCHUNK + c) * DI + d;
    float hl = hLH[base * 16 + n];
    float T = Tsum[base];
    float hprev = h;
    h = fmaf(__expf(a * T), h, hl);
    hLH[base * 16 + n] = hprev;
  }
}

// ---------------- K5c: replay chunk with H_init + fused epilogue -----------
__global__ __launch_bounds__(256) void scan_part3(
    const float* __restrict__ xc,
    const short* __restrict__ xz,    // read z (bf16) at cols 1536..
    short* __restrict__ ybf,
    const float* __restrict__ Bm, const float* __restrict__ Cm,
    const float* __restrict__ dtr,
    const float* __restrict__ w_dt, const float* __restrict__ b_dt,
    const float* __restrict__ A_log, const float* __restrict__ Dp,
    const float* __restrict__ Hinit)
{
  const int blk = blockIdx.x;
  const int c  = blk % NCHUNK;
  const int db = (blk / NCHUNK) % (DI / 256);
  const int b  = blk / (NCHUNK * (DI / 256));
  const int tid = threadIdx.x;
  const int d = db * 256 + tid;
  const size_t cb = (size_t)b * SEQN + c * CHUNK;

  __shared__ float sB[CHUNK][16], sC[CHUNK][16];
  __shared__ float sdt[CHUNK];
  if (tid < CHUNK * 4)
    reinterpret_cast<float4*>(&sB[0][0])[tid] =
        reinterpret_cast<const float4*>(&Bm[cb * 16])[tid];
  else if (tid < CHUNK * 8)
    reinterpret_cast<float4*>(&sC[0][0])[tid - CHUNK * 4] =
        reinterpret_cast<const float4*>(&Cm[cb * 16])[tid - CHUNK * 4];
  if (tid < CHUNK / 4)
    reinterpret_cast<float4*>(sdt)[tid] =
        reinterpret_cast<const float4*>(&dtr[cb])[tid];

  const float wdt = w_dt[d], bdt = b_dt[d];
  const float Dd = Dp[d];
  float a[DS2], h[DS2];
#pragma unroll
  for (int q = 0; q < 4; ++q) {
    float4 al = *reinterpret_cast<const float4*>(&A_log[(size_t)d * DS2 + q * 4]);
    a[q * 4 + 0] = -__expf(al.x); a[q * 4 + 1] = -__expf(al.y);
    a[q * 4 + 2] = -__expf(al.z); a[q * 4 + 3] = -__expf(al.w);
  }
  const size_t base = (size_t)(b * NCHUNK + c) * DI + d;
#pragma unroll
  for (int q = 0; q < 4; ++q)
    *reinterpret_cast<float4*>(&h[q * 4]) =
        *reinterpret_cast<const float4*>(&Hinit[base * 16 + q * 4]);
  __syncthreads();

#pragma unroll 2
  for (int tt = 0; tt < CHUNK; ++tt) {
    float v = fmaf(sdt[tt], wdt, bdt);
    float dtv = (v > 15.f) ? v : __logf(1.f + __expf(v));
    float xv = xc[(cb + tt) * DI + d];
    float s = dtv * xv;
    float bb[DS2], cc[DS2];
#pragma unroll
    for (int q = 0; q < 4; ++q) {
      *reinterpret_cast<float4*>(&bb[q * 4]) =
          *reinterpret_cast<const float4*>(&sB[tt][q * 4]);
      *reinterpret_cast<float4*>(&cc[q * 4]) =
          *reinterpret_cast<const float4*>(&sC[tt][q * 4]);
    }
    float y = 0.f;
#pragma unroll
    for (int n = 0; n < DS2; ++n) {
      h[n] = fmaf(__expf(a[n] * dtv), h[n], s * bb[n]);
      y = fmaf(h[n], cc[n], y);
    }
    const size_t rr = cb + tt;
    float z = bf2f(xz[rr * 3072 + DI + d]);
    float yo = fmaf(xv, Dd, y);
    ybf[rr * DI + d] = (short)f2bf(yo * (z / (1.f + __expf(-z))));
  }
}

// ---------------- launcher -------------------------------------------------
extern "C" void kernel_launch(void* const* d_in, const int* in_sizes, int n_in,
                              void* d_out, int out_size, void* d_ws, size_t ws_size,
                              hipStream_t stream) {
  const float* x      = (const float*)d_in[0];
  const float* norm_w = (const float*)d_in[1];
  const float* w_in   = (const float*)d_in[2];
  const float* conv_w = (const float*)d_in[3];
  const float* conv_b = (const float*)d_in[4];
  const float* w_x    = (const float*)d_in[5];
  const float* w_dt   = (const float*)d_in[6];
  const float* b_dt   = (const float*)d_in[7];
  const float* A_log  = (const float*)d_in[8];
  const float* Dp     = (const float*)d_in[9];
  const float* w_out  = (const float*)d_in[10];
  float* out = (float*)d_out;

  // workspace layout
  float* ws   = (float*)d_ws;
  float* xc   = ws;                          // 4096 x 1536 f32
  float* Bm   = xc + (size_t)NROWS * DI;     // 4096 x 16
  float* Cm   = Bm + (size_t)NROWS * 16;
  float* dtr  = Cm + (size_t)NROWS * 16;     // 4096
  float* rinv = dtr + NROWS;                 // 4096
  float* hL   = rinv + NROWS;                // B*NCHUNK*DI*16 = 3.1M
  float* Tsum = hL + (size_t)BSZ * NCHUNK * DI * 16;  // 196K
  float* wxT  = Tsum + (size_t)BSZ * NCHUNK * DI;     // 33*1536
  short* xzb  = (short*)(wxT + (size_t)33 * DI);      // 4096 x 3072 bf16
  short* xnb  = xzb + (size_t)NROWS * 2 * DI;         // 4096 x 768 bf16
  short* winT = xnb + (size_t)NROWS * DM;             // 3072 x 768 bf16
  short* woutT= winT + (size_t)2 * DI * DM;           // 768 x 1536 bf16
  short* ybf  = woutT + (size_t)DM * DI;              // 4096 x 1536 bf16
  // total ~90 MB

  rms_k<<<NROWS / 4, 256, 0, stream>>>(x, rinv);
  cvt_xn_k<<<(NROWS * DM / 4) / 256, 256, 0, stream>>>(x, rinv, norm_w, xnb);
  cvt_transpose_k<<<dim3(2 * DI / 32, DM / 32), 256, 0, stream>>>(w_in, DM, 2 * DI, winT);
  cvt_transpose_k<<<dim3(DM / 32, DI / 32), 256, 0, stream>>>(w_out, DI, DM, woutT);
  wxT_k<<<(DI * 33 + 255) / 256, 256, 0, stream>>>(w_x, wxT);

  // GEMM1: xz(bf16) = xn @ w_in   (M=4096 N=3072 K=768), 128x128 tile
  gemm_bf16<128, 128, true><<<dim3(2 * DI / 128, NROWS / 128), 256, 0, stream>>>(
      xnb, DM, winT, DM, xzb, 2 * DI, DM, nullptr, 0);

  conv_silu_k<<<(NROWS * DI) / 256, 256, 0, stream>>>(xzb, conv_w, conv_b, xc);
  xssm_k<<<NROWS / 8, 256, 0, stream>>>(xc, wxT, Bm, Cm, dtr);

  const int nblk = BSZ * (DI / 256) * NCHUNK;  // 768
  scan_part1<<<nblk, 256, 0, stream>>>(xc, Bm, dtr, w_dt, b_dt, A_log, hL, Tsum);
  scan_combine_k<<<(BSZ * DI * DS2) / 256, 256, 0, stream>>>(hL, Tsum, A_log);
  scan_part3<<<nblk, 256, 0, stream>>>(xc, xzb, ybf, Bm, Cm, dtr, w_dt, b_dt,
                                       A_log, Dp, hL);

  // GEMM3: out = x + y @ w_out   (M=4096 N=768 K=1536), 64x64 tile -> 768 blk
  gemm_bf16<64, 64, false><<<dim3(DM / 64, NROWS / 64), 256, 0, stream>>>(
      ybf, DI, woutT, DI, out, DM, DI, x, DM);
}